// Round 3
// baseline (1352.431 us; speedup 1.0000x reference)
//
#include <hip/hip_runtime.h>

#define D_FEAT 64
#define H_SIZE 32
#define N_CLASSES 10
#define NPB 256          // nodes per bucket (bucket = dst >> 8)
#define MAXB 512         // max buckets supported
#define NCHUNK 256       // edge chunks for count/scatter passes
#define BT 1024          // big block (16 waves)
#define NT 256
#define SCAN_T 1024

// ---------- dense1: xr = x@W1_rel^T ; xroot = x@W1_root^T + b1 -------------

__global__ __launch_bounds__(NT) void dense1_kernel(
    const float* __restrict__ x, const float* __restrict__ W1_rel,
    const float* __restrict__ b1, const float* __restrict__ W1_root,
    float* __restrict__ xr, float* __restrict__ xroot, int n_nodes) {
    __shared__ float sWrelT[D_FEAT * H_SIZE];   // [f][k]
    __shared__ float sWrootT[D_FEAT * H_SIZE];
    __shared__ float sb[H_SIZE];
    for (int i = threadIdx.x; i < H_SIZE * D_FEAT; i += NT) {
        int k = i >> 6, f = i & 63;
        sWrelT[f * H_SIZE + k] = W1_rel[i];
        sWrootT[f * H_SIZE + k] = W1_root[i];
    }
    if (threadIdx.x < H_SIZE) sb[threadIdx.x] = b1[threadIdx.x];
    __syncthreads();

    int t = blockIdx.x * NT + threadIdx.x;
    int n = t >> 5, k = t & 31;
    if (n >= n_nodes) return;
    const float* xrow = x + (size_t)n * D_FEAT;
    float ar = 0.f, ao = 0.f;
#pragma unroll
    for (int f = 0; f < D_FEAT; ++f) {
        float xv = xrow[f];
        ar += xv * sWrelT[f * H_SIZE + k];
        ao += xv * sWrootT[f * H_SIZE + k];
    }
    xr[n * H_SIZE + k] = ar;
    xroot[n * H_SIZE + k] = ao + sb[k];
}

// ---------- bucket count / scan / scatter ----------------------------------

__global__ __launch_bounds__(BT) void bucket_count(
    const int* __restrict__ dst, int* __restrict__ counts,
    int n_edges, int nbuckets, int ept) {
    __shared__ int hist[MAXB];
    for (int i = threadIdx.x; i < nbuckets; i += BT) hist[i] = 0;
    __syncthreads();
    int beg = blockIdx.x * ept;
    int end = min(beg + ept, n_edges);
    for (int e = beg + threadIdx.x; e < end; e += BT)
        atomicAdd(&hist[dst[e] >> 8], 1);
    __syncthreads();
    for (int b = threadIdx.x; b < nbuckets; b += BT)
        counts[b * NCHUNK + blockIdx.x] = hist[b];
}

// exclusive scan in place over a[0..M); writes a[M] = total
__global__ __launch_bounds__(SCAN_T) void scan_excl(int* __restrict__ a, int M) {
    __shared__ int lds[SCAN_T];
    int tid = threadIdx.x;
    int R = (M + SCAN_T - 1) / SCAN_T;
    int beg = tid * R, end = min(beg + R, M);
    int s = 0;
    for (int i = beg; i < end; ++i) s += a[i];
    lds[tid] = s;
    __syncthreads();
    for (int off = 1; off < SCAN_T; off <<= 1) {
        int v = (tid >= off) ? lds[tid - off] : 0;
        __syncthreads();
        lds[tid] += v;
        __syncthreads();
    }
    int run = lds[tid] - s;
    for (int i = beg; i < end; ++i) { int v = a[i]; a[i] = run; run += v; }
    if (beg < M && end == M) a[M] = run;
}

__global__ __launch_bounds__(BT) void bucket_scatter(
    const int* __restrict__ src, const int* __restrict__ dst,
    const int* __restrict__ base, unsigned* __restrict__ packed,
    int n_edges, int nbuckets, int ept) {
    __shared__ int cur[MAXB];
    for (int b = threadIdx.x; b < nbuckets; b += BT)
        cur[b] = base[b * NCHUNK + blockIdx.x];
    __syncthreads();
    int beg = blockIdx.x * ept;
    int end = min(beg + ept, n_edges);
    for (int e = beg + threadIdx.x; e < end; e += BT) {
        int s = src[e], d = dst[e];
        int slot = atomicAdd(&cur[d >> 8], 1);
        packed[slot] = (unsigned)s | ((unsigned)(d & 255) << 24);
    }
}

// ---------- layer-1 aggregate + relu + fused dense2 ------------------------

__global__ __launch_bounds__(BT) void agg1_kernel(
    const unsigned* __restrict__ packed, const int* __restrict__ base,
    const float* __restrict__ xr, const float* __restrict__ xroot,
    const float* __restrict__ W2_rel, const float* __restrict__ b2,
    const float* __restrict__ W2_root,
    float* __restrict__ h2, float* __restrict__ hroot,
    int n_nodes, int nbuckets, int n_edges) {
    __shared__ float agg[NPB * 33];          // pad 33: conflict-free
    __shared__ float sWrelT[H_SIZE * 16];    // [j][c], c>=10 zero
    __shared__ float sWrootT[H_SIZE * 16];
    __shared__ float sb2[16];
    int tid = threadIdx.x;
    int b = blockIdx.x;
    for (int i = tid; i < NPB * 33; i += BT) agg[i] = 0.f;
    for (int i = tid; i < H_SIZE * 16; i += BT) {
        int j = i >> 4, c = i & 15;
        sWrelT[i]  = (c < N_CLASSES) ? W2_rel[c * H_SIZE + j]  : 0.f;
        sWrootT[i] = (c < N_CLASSES) ? W2_root[c * H_SIZE + j] : 0.f;
    }
    if (tid < 16) sb2[tid] = (tid < N_CLASSES) ? b2[tid] : 0.f;
    __syncthreads();

    int pBeg = base[b * NCHUNK];
    int pEnd = (b + 1 < nbuckets) ? base[(b + 1) * NCHUNK] : n_edges;
    int f = tid & 31;
    int g = tid >> 5;                        // 32 edge-groups
    for (int i0 = pBeg + g * 4; i0 < pEnd; i0 += 32 * 4) {
#pragma unroll
        for (int u = 0; u < 4; ++u) {
            int i = i0 + u;
            if (i < pEnd) {
                unsigned p = packed[i];      // broadcast across 32 lanes
                int s  = p & 0xFFFFFF;
                int dl = p >> 24;
                float v = xr[s * H_SIZE + f];
                atomicAdd(&agg[dl * 33 + f], v);
            }
        }
    }
    __syncthreads();

    int bBase = b << 8;
    // fold root + bias + relu
    for (int idx = tid; idx < NPB * H_SIZE; idx += BT) {
        int nl = idx >> 5, j = idx & 31;
        int n = bBase + nl;
        float v = 0.f;
        if (n < n_nodes) v = fmaxf(agg[nl * 33 + j] + xroot[n * H_SIZE + j], 0.f);
        agg[nl * 33 + j] = v;
    }
    __syncthreads();
    // fused dense2: h2 = h@W2_rel^T (pad 16), hroot = h@W2_root^T + b2
#pragma unroll
    for (int pass = 0; pass < (NPB * 16) / BT; ++pass) {
        int idx = pass * BT + tid;
        int nl = idx >> 4, c = idx & 15;
        int n = bBase + nl;
        if (n < n_nodes) {
            float ar = 0.f, ao = 0.f;
#pragma unroll
            for (int j = 0; j < H_SIZE; ++j) {
                float hv = agg[nl * 33 + j];
                ar += hv * sWrelT[j * 16 + c];
                ao += hv * sWrootT[j * 16 + c];
            }
            h2[n * 16 + c] = ar;
            hroot[n * 16 + c] = ao + sb2[c];
        }
    }
}

// ---------- layer-2 aggregate + log-softmax + NLL --------------------------

__global__ __launch_bounds__(BT) void agg2_loss_kernel(
    const unsigned* __restrict__ packed, const int* __restrict__ base,
    const float* __restrict__ h2, const float* __restrict__ hroot,
    const int* __restrict__ y, float* __restrict__ loss,
    int n_nodes, int nbuckets, int n_edges, float invN) {
    __shared__ float logits[NPB * 17];       // pad 17
    __shared__ float part[BT / 64];
    int tid = threadIdx.x;
    int b = blockIdx.x;
    for (int i = tid; i < NPB * 17; i += BT) logits[i] = 0.f;
    __syncthreads();

    int pBeg = base[b * NCHUNK];
    int pEnd = (b + 1 < nbuckets) ? base[(b + 1) * NCHUNK] : n_edges;
    int f = tid & 15;
    int g = tid >> 4;                        // 64 edge-groups
    for (int i0 = pBeg + g * 4; i0 < pEnd; i0 += 64 * 4) {
#pragma unroll
        for (int u = 0; u < 4; ++u) {
            int i = i0 + u;
            if (i < pEnd) {
                unsigned p = packed[i];
                int s  = p & 0xFFFFFF;
                int dl = p >> 24;
                atomicAdd(&logits[dl * 17 + f], h2[s * 16 + f]);
            }
        }
    }
    __syncthreads();

    int bBase = b << 8;
    for (int idx = tid; idx < NPB * 16; idx += BT) {
        int nl = idx >> 4, c = idx & 15;
        int n = bBase + nl;
        if (n < n_nodes) logits[nl * 17 + c] += hroot[n * 16 + c];
    }
    __syncthreads();

    float contrib = 0.f;
    if (tid < NPB) {
        int n = bBase + tid;
        if (n < n_nodes) {
            float l[N_CLASSES];
#pragma unroll
            for (int c = 0; c < N_CLASSES; ++c) l[c] = logits[tid * 17 + c];
            float m = l[0];
#pragma unroll
            for (int c = 1; c < N_CLASSES; ++c) m = fmaxf(m, l[c]);
            float s = 0.f;
#pragma unroll
            for (int c = 0; c < N_CLASSES; ++c) s += expf(l[c] - m);
            float lse = m + logf(s);
            int yv = y[n];
            float ly = 0.f;
#pragma unroll
            for (int c = 0; c < N_CLASSES; ++c) ly = (c == yv) ? l[c] : ly;
            contrib = (lse - ly) * invN;
        }
    }
#pragma unroll
    for (int o = 32; o > 0; o >>= 1) contrib += __shfl_down(contrib, o, 64);
    if ((tid & 63) == 0) part[tid >> 6] = contrib;
    __syncthreads();
    if (tid == 0) {
        float v = 0.f;
#pragma unroll
        for (int w = 0; w < BT / 64; ++w) v += part[w];
        atomicAdd(loss, v);
    }
}

// ---------------------------------------------------------------------------

extern "C" void kernel_launch(void* const* d_in, const int* in_sizes, int n_in,
                              void* d_out, int out_size, void* d_ws, size_t ws_size,
                              hipStream_t stream) {
    const float* x       = (const float*)d_in[0];
    const int*   ei      = (const int*)d_in[1];
    const int*   y       = (const int*)d_in[2];
    const float* W1_rel  = (const float*)d_in[3];
    const float* b1_rel  = (const float*)d_in[4];
    const float* W1_root = (const float*)d_in[5];
    const float* W2_rel  = (const float*)d_in[6];
    const float* b2_rel  = (const float*)d_in[7];
    const float* W2_root = (const float*)d_in[8];
    float* loss = (float*)d_out;

    const int n_nodes = in_sizes[0] / D_FEAT;
    const int n_edges = in_sizes[1] / 2;
    const int* src = ei;
    const int* dst = ei + n_edges;

    const int nbuckets = (n_nodes + NPB - 1) / NPB;       // 391
    const int M = nbuckets * NCHUNK;
    const int ept = (n_edges + NCHUNK - 1) / NCHUNK;      // edges per chunk

    size_t off = 0;
    auto alloc = [&](size_t bytes) {
        void* p = (char*)d_ws + off;
        off = (off + bytes + 255) & ~(size_t)255;
        return p;
    };
    int*      counts = (int*)alloc((size_t)(M + 1) * 4);
    unsigned* packed = (unsigned*)alloc((size_t)n_edges * 4);
    float*    xr     = (float*)alloc((size_t)n_nodes * H_SIZE * 4);
    float*    xroot  = (float*)alloc((size_t)n_nodes * H_SIZE * 4);
    float*    h2     = (float*)alloc((size_t)n_nodes * 16 * 4);
    float*    hroot  = (float*)alloc((size_t)n_nodes * 16 * 4);

    // dense pre-transform (independent of bucketing)
    dense1_kernel<<<(n_nodes * H_SIZE + NT - 1) / NT, NT, 0, stream>>>(
        x, W1_rel, b1_rel, W1_root, xr, xroot, n_nodes);

    // bucket build
    bucket_count<<<NCHUNK, BT, 0, stream>>>(dst, counts, n_edges, nbuckets, ept);
    scan_excl<<<1, SCAN_T, 0, stream>>>(counts, M);
    bucket_scatter<<<NCHUNK, BT, 0, stream>>>(src, dst, counts, packed,
                                              n_edges, nbuckets, ept);

    // layer 1 aggregate + fused dense2
    agg1_kernel<<<nbuckets, BT, 0, stream>>>(packed, counts, xr, xroot,
                                             W2_rel, b2_rel, W2_root,
                                             h2, hroot, n_nodes, nbuckets, n_edges);

    // layer 2 aggregate + loss
    hipMemsetAsync(loss, 0, sizeof(float), stream);
    agg2_loss_kernel<<<nbuckets, BT, 0, stream>>>(packed, counts, h2, hroot, y, loss,
                                                  n_nodes, nbuckets, n_edges,
                                                  1.f / (float)n_nodes);
}

// Round 4
// 559.682 us; speedup vs baseline: 2.4164x; 2.4164x over previous
//
#include <hip/hip_runtime.h>

#define D_FEAT 64
#define H_SIZE 32
#define N_CLASSES 10
#define NPB 256          // nodes per bucket (bucket = dst >> 8)
#define MAXB 512
#define NCHUNK 256       // edge chunks for count/scatter passes
#define BT 1024
#define NT 256
#define SCAN_T 1024

// ---------- dense1: xr = x@W1_rel^T ; xroot = x@W1_root^T + b1 -------------

__global__ __launch_bounds__(NT) void dense1_kernel(
    const float* __restrict__ x, const float* __restrict__ W1_rel,
    const float* __restrict__ b1, const float* __restrict__ W1_root,
    float* __restrict__ xr, float* __restrict__ xroot, int n_nodes) {
    __shared__ float sWrelT[D_FEAT * H_SIZE];   // [f][k]
    __shared__ float sWrootT[D_FEAT * H_SIZE];
    __shared__ float sb[H_SIZE];
    for (int i = threadIdx.x; i < H_SIZE * D_FEAT; i += NT) {
        int k = i >> 6, f = i & 63;
        sWrelT[f * H_SIZE + k] = W1_rel[i];
        sWrootT[f * H_SIZE + k] = W1_root[i];
    }
    if (threadIdx.x < H_SIZE) sb[threadIdx.x] = b1[threadIdx.x];
    __syncthreads();

    int t = blockIdx.x * NT + threadIdx.x;
    int n = t >> 5, k = t & 31;
    if (n >= n_nodes) return;
    const float* xrow = x + (size_t)n * D_FEAT;
    float ar = 0.f, ao = 0.f;
#pragma unroll
    for (int f = 0; f < D_FEAT; ++f) {
        float xv = xrow[f];
        ar += xv * sWrelT[f * H_SIZE + k];
        ao += xv * sWrootT[f * H_SIZE + k];
    }
    xr[n * H_SIZE + k] = ar;
    xroot[n * H_SIZE + k] = ao + sb[k];
}

// ---------- bucket count / scan / scatter (proven cheap in R3) -------------

__global__ __launch_bounds__(BT) void bucket_count(
    const int* __restrict__ dst, int* __restrict__ counts,
    int n_edges, int nbuckets, int ept) {
    __shared__ int hist[MAXB];
    for (int i = threadIdx.x; i < nbuckets; i += BT) hist[i] = 0;
    __syncthreads();
    int beg = blockIdx.x * ept;
    int end = min(beg + ept, n_edges);
    for (int e = beg + threadIdx.x; e < end; e += BT)
        atomicAdd(&hist[dst[e] >> 8], 1);
    __syncthreads();
    for (int b = threadIdx.x; b < nbuckets; b += BT)
        counts[b * NCHUNK + blockIdx.x] = hist[b];
}

__global__ __launch_bounds__(SCAN_T) void scan_excl(int* __restrict__ a, int M) {
    __shared__ int lds[SCAN_T];
    int tid = threadIdx.x;
    int R = (M + SCAN_T - 1) / SCAN_T;
    int beg = tid * R, end = min(beg + R, M);
    int s = 0;
    for (int i = beg; i < end; ++i) s += a[i];
    lds[tid] = s;
    __syncthreads();
    for (int off = 1; off < SCAN_T; off <<= 1) {
        int v = (tid >= off) ? lds[tid - off] : 0;
        __syncthreads();
        lds[tid] += v;
        __syncthreads();
    }
    int run = lds[tid] - s;
    for (int i = beg; i < end; ++i) { int v = a[i]; a[i] = run; run += v; }
    if (beg < M && end == M) a[M] = run;
}

__global__ __launch_bounds__(BT) void bucket_scatter(
    const int* __restrict__ src, const int* __restrict__ dst,
    const int* __restrict__ base, unsigned* __restrict__ packed,
    int n_edges, int nbuckets, int ept) {
    __shared__ int cur[MAXB];
    for (int b = threadIdx.x; b < nbuckets; b += BT)
        cur[b] = base[b * NCHUNK + blockIdx.x];
    __syncthreads();
    int beg = blockIdx.x * ept;
    int end = min(beg + ept, n_edges);
    for (int e = beg + threadIdx.x; e < end; e += BT) {
        int s = src[e], d = dst[e];
        int slot = atomicAdd(&cur[d >> 8], 1);
        packed[slot] = (unsigned)s | ((unsigned)(d & 255) << 24);
    }
}

// ---------- per-bucket counting sort -> global CSR -------------------------
// writes confined to one ~32KB window per block: no write amplification

__global__ __launch_bounds__(NPB) void csr_build(
    const unsigned* __restrict__ packed, const int* __restrict__ base,
    int* __restrict__ rowptr, int* __restrict__ csr,
    int n_nodes, int nbuckets, int n_edges) {
    __shared__ int cnt[NPB];
    __shared__ int cur[NPB];
    int b = blockIdx.x, tid = threadIdx.x;
    int pBeg = base[b * NCHUNK];
    int pEnd = (b + 1 < nbuckets) ? base[(b + 1) * NCHUNK] : n_edges;
    cnt[tid] = 0;
    __syncthreads();
    for (int i = pBeg + tid; i < pEnd; i += NPB)
        atomicAdd(&cnt[packed[i] >> 24], 1);
    __syncthreads();
    // exclusive scan over 256 ints (Hillis-Steele)
    int v = cnt[tid];
    cur[tid] = v;
    __syncthreads();
    for (int off = 1; off < NPB; off <<= 1) {
        int t = (tid >= off) ? cur[tid - off] : 0;
        __syncthreads();
        cur[tid] += t;
        __syncthreads();
    }
    int gbase = pBeg + cur[tid] - v;   // exclusive prefix
    int n = (b << 8) + tid;
    if (n < n_nodes) rowptr[n] = gbase;
    if (b == nbuckets - 1 && tid == 0) rowptr[n_nodes] = n_edges;
    cur[tid] = gbase;                  // reuse as cursor
    __syncthreads();
    for (int i = pBeg + tid; i < pEnd; i += NPB) {
        unsigned p = packed[i];
        int slot = atomicAdd(&cur[p >> 24], 1);
        csr[slot] = (int)(p & 0xFFFFFF);
    }
}

// ---------- gather1: h = relu(gather_sum(xr) + xroot) ----------------------
// 32 lanes per node; coalesced csr loads redistributed by shfl; unroll 16.
// NOTE: h aliases xroot (same-element read-then-write per thread) -> no restrict

__global__ __launch_bounds__(NT) void gather1_kernel(
    const float* __restrict__ xr, const float* xroot,
    const int* __restrict__ rowptr, const int* __restrict__ csr,
    float* h, int n_nodes) {
    int t = blockIdx.x * NT + threadIdx.x;
    int n = t >> 5, f = t & 31;
    if (n >= n_nodes) return;
    int beg = rowptr[n], end = rowptr[n + 1];
    float acc = 0.f;
    for (int i = beg; i < end; i += 16) {
        int cnt = end - i;
        int idx = f & 15;
        int e = csr[i + ((idx < cnt) ? idx : cnt - 1)];  // coalesced 16-wide
#pragma unroll
        for (int j = 0; j < 16; ++j) {
            int s = __shfl(e, j, 16);
            float v = xr[(size_t)s * H_SIZE + f];
            if (j < cnt) acc += v;
        }
    }
    h[(size_t)n * H_SIZE + f] = fmaxf(acc + xroot[(size_t)n * H_SIZE + f], 0.f);
}

// ---------- dense2: h2 = h@W2_rel^T ; hroot = h@W2_root^T + b2 (pad 16) ----

__global__ __launch_bounds__(NT) void dense2_kernel(
    const float* __restrict__ h, const float* __restrict__ W2_rel,
    const float* __restrict__ b2, const float* __restrict__ W2_root,
    float* __restrict__ h2, float* __restrict__ hroot, int n_nodes) {
    __shared__ float sWrelT[H_SIZE * 16];   // [j][c]
    __shared__ float sWrootT[H_SIZE * 16];
    __shared__ float sb[16];
    for (int i = threadIdx.x; i < H_SIZE * 16; i += NT) sWrelT[i] = sWrootT[i] = 0.f;
    __syncthreads();
    for (int i = threadIdx.x; i < N_CLASSES * H_SIZE; i += NT) {
        int c = i >> 5, j = i & 31;
        sWrelT[j * 16 + c] = W2_rel[i];
        sWrootT[j * 16 + c] = W2_root[i];
    }
    if (threadIdx.x < 16) sb[threadIdx.x] = (threadIdx.x < N_CLASSES) ? b2[threadIdx.x] : 0.f;
    __syncthreads();

    int t = blockIdx.x * NT + threadIdx.x;
    int n = t >> 4, c = t & 15;
    if (n >= n_nodes) return;
    const float* hrow = h + (size_t)n * H_SIZE;
    float ar = 0.f, ao = 0.f;
#pragma unroll
    for (int j = 0; j < H_SIZE; ++j) {
        float hv = hrow[j];
        ar += hv * sWrelT[j * 16 + c];
        ao += hv * sWrootT[j * 16 + c];
    }
    bool valid = (c < N_CLASSES);
    h2[n * 16 + c] = valid ? ar : 0.f;
    hroot[n * 16 + c] = valid ? (ao + sb[c]) : 0.f;
}

// ---------- gather2 + log-softmax + NLL ------------------------------------

__global__ __launch_bounds__(NT) void gather2_loss_kernel(
    const float* __restrict__ h2, const float* __restrict__ hroot,
    const int* __restrict__ rowptr, const int* __restrict__ csr,
    const int* __restrict__ y, float* __restrict__ loss,
    int n_nodes, float invN) {
    int t = blockIdx.x * NT + threadIdx.x;
    int n = t >> 4, c = t & 15;
    int lane = threadIdx.x & 63;
    bool active = (n < n_nodes);

    float logit = 0.f;
    int yv = 0;
    if (active) {
        int beg = rowptr[n], end = rowptr[n + 1];
        float acc = 0.f;
        for (int i = beg; i < end; i += 16) {
            int cnt = end - i;
            int e = csr[i + ((c < cnt) ? c : cnt - 1)];
#pragma unroll
            for (int j = 0; j < 16; ++j) {
                int s = __shfl(e, j, 16);
                float v = h2[(size_t)s * 16 + c];
                if (j < cnt) acc += v;
            }
        }
        logit = acc + hroot[(size_t)n * 16 + c];
        yv = y[n];
    }
    float lm = (active && c < N_CLASSES) ? logit : -INFINITY;
#pragma unroll
    for (int m = 1; m < 16; m <<= 1) lm = fmaxf(lm, __shfl_xor(lm, m, 64));
    float e = (active && c < N_CLASSES) ? expf(logit - lm) : 0.f;
#pragma unroll
    for (int m = 1; m < 16; m <<= 1) e += __shfl_xor(e, m, 64);
    float ly = __shfl(logit, (lane & ~15) + yv, 64);
    float contrib = (active && c == 0) ? (lm + logf(e) - ly) * invN : 0.f;

#pragma unroll
    for (int o = 32; o > 0; o >>= 1) contrib += __shfl_down(contrib, o, 64);
    __shared__ float part[NT / 64];
    if (lane == 0) part[threadIdx.x >> 6] = contrib;
    __syncthreads();
    if (threadIdx.x == 0) {
        float v = 0.f;
#pragma unroll
        for (int w = 0; w < NT / 64; ++w) v += part[w];
        atomicAdd(loss, v);
    }
}

// ---------------------------------------------------------------------------

extern "C" void kernel_launch(void* const* d_in, const int* in_sizes, int n_in,
                              void* d_out, int out_size, void* d_ws, size_t ws_size,
                              hipStream_t stream) {
    const float* x       = (const float*)d_in[0];
    const int*   ei      = (const int*)d_in[1];
    const int*   y       = (const int*)d_in[2];
    const float* W1_rel  = (const float*)d_in[3];
    const float* b1_rel  = (const float*)d_in[4];
    const float* W1_root = (const float*)d_in[5];
    const float* W2_rel  = (const float*)d_in[6];
    const float* b2_rel  = (const float*)d_in[7];
    const float* W2_root = (const float*)d_in[8];
    float* loss = (float*)d_out;

    const int n_nodes = in_sizes[0] / D_FEAT;
    const int n_edges = in_sizes[1] / 2;
    const int* src = ei;
    const int* dst = ei + n_edges;

    const int nbuckets = (n_nodes + NPB - 1) / NPB;
    const int M = nbuckets * NCHUNK;
    const int ept = (n_edges + NCHUNK - 1) / NCHUNK;

    size_t off = 0;
    auto alloc = [&](size_t bytes) {
        void* p = (char*)d_ws + off;
        off = (off + bytes + 255) & ~(size_t)255;
        return p;
    };
    int*      counts = (int*)alloc((size_t)(M + 1) * 4);
    unsigned* packed = (unsigned*)alloc((size_t)n_edges * 4);
    int*      rowptr = (int*)alloc((size_t)(n_nodes + 1) * 4);
    int*      csr    = (int*)alloc((size_t)n_edges * 4);
    float*    xr     = (float*)alloc((size_t)n_nodes * H_SIZE * 4);
    float*    xroot  = (float*)alloc((size_t)n_nodes * H_SIZE * 4);  // h aliases
    float*    h2     = (float*)alloc((size_t)n_nodes * 16 * 4);
    float*    hroot  = (float*)alloc((size_t)n_nodes * 16 * 4);
    float*    h      = xroot;

    // dense pre-transform
    dense1_kernel<<<(n_nodes * H_SIZE + NT - 1) / NT, NT, 0, stream>>>(
        x, W1_rel, b1_rel, W1_root, xr, xroot, n_nodes);

    // bucket build -> packed -> CSR
    bucket_count<<<NCHUNK, BT, 0, stream>>>(dst, counts, n_edges, nbuckets, ept);
    scan_excl<<<1, SCAN_T, 0, stream>>>(counts, M);
    bucket_scatter<<<NCHUNK, BT, 0, stream>>>(src, dst, counts, packed,
                                              n_edges, nbuckets, ept);
    csr_build<<<nbuckets, NPB, 0, stream>>>(packed, counts, rowptr, csr,
                                            n_nodes, nbuckets, n_edges);

    // layer 1
    gather1_kernel<<<(n_nodes * H_SIZE + NT - 1) / NT, NT, 0, stream>>>(
        xr, xroot, rowptr, csr, h, n_nodes);

    // layer 2 + loss
    dense2_kernel<<<(n_nodes * 16 + NT - 1) / NT, NT, 0, stream>>>(
        h, W2_rel, b2_rel, W2_root, h2, hroot, n_nodes);
    hipMemsetAsync(loss, 0, sizeof(float), stream);
    gather2_loss_kernel<<<(n_nodes * 16 + NT - 1) / NT, NT, 0, stream>>>(
        h2, hroot, rowptr, csr, y, loss, n_nodes, 1.f / (float)n_nodes);
}

// Round 5
// 404.112 us; speedup vs baseline: 3.3467x; 1.3850x over previous
//
#include <hip/hip_runtime.h>

#define D_FEAT 64
#define H_SIZE 32
#define N_CLASSES 10
#define NPB 256          // nodes per bucket (bucket = dst >> 8)
#define MAXB 512
#define NCHUNK 256       // edge chunks for count/scatter passes
#define BT 1024
#define NT 256

// ---------- dense1: xr = x@W1_rel^T ; xroot = x@W1_root^T + b1 -------------

__global__ __launch_bounds__(NT) void dense1_kernel(
    const float* __restrict__ x, const float* __restrict__ W1_rel,
    const float* __restrict__ b1, const float* __restrict__ W1_root,
    float* __restrict__ xr, float* __restrict__ xroot, int n_nodes) {
    __shared__ float sWrelT[D_FEAT * H_SIZE];   // [f][k]
    __shared__ float sWrootT[D_FEAT * H_SIZE];
    __shared__ float sb[H_SIZE];
    for (int i = threadIdx.x; i < H_SIZE * D_FEAT; i += NT) {
        int k = i >> 6, f = i & 63;
        sWrelT[f * H_SIZE + k] = W1_rel[i];
        sWrootT[f * H_SIZE + k] = W1_root[i];
    }
    if (threadIdx.x < H_SIZE) sb[threadIdx.x] = b1[threadIdx.x];
    __syncthreads();

    int t = blockIdx.x * NT + threadIdx.x;
    int n = t >> 5, k = t & 31;
    if (n >= n_nodes) return;
    const float* xrow = x + (size_t)n * D_FEAT;
    float ar = 0.f, ao = 0.f;
#pragma unroll
    for (int f = 0; f < D_FEAT; ++f) {
        float xv = xrow[f];
        ar += xv * sWrelT[f * H_SIZE + k];
        ao += xv * sWrootT[f * H_SIZE + k];
    }
    xr[n * H_SIZE + k] = ar;
    xroot[n * H_SIZE + k] = ao + sb[k];
}

// ---------- bucket count -> hierarchical scan -> scatter -------------------

__global__ __launch_bounds__(BT) void bucket_count(
    const int* __restrict__ dst, int* __restrict__ counts,
    int n_edges, int nbuckets, int ept) {
    __shared__ int hist[MAXB];
    for (int i = threadIdx.x; i < nbuckets; i += BT) hist[i] = 0;
    __syncthreads();
    int beg = blockIdx.x * ept;
    int end = min(beg + ept, n_edges);
    for (int e = beg + threadIdx.x; e < end; e += BT)
        atomicAdd(&hist[dst[e] >> 8], 1);
    __syncthreads();
    for (int b = threadIdx.x; b < nbuckets; b += BT)
        counts[b * NCHUNK + blockIdx.x] = hist[b];
}

// 1) per-bucket totals (one block per bucket)
__global__ __launch_bounds__(NPB) void bucket_totals(
    const int* __restrict__ counts, int* __restrict__ totals) {
    int b = blockIdx.x, tid = threadIdx.x;
    int v = counts[b * NCHUNK + tid];
#pragma unroll
    for (int o = 32; o > 0; o >>= 1) v += __shfl_down(v, o, 64);
    __shared__ int part[NPB / 64];
    if ((tid & 63) == 0) part[tid >> 6] = v;
    __syncthreads();
    if (tid == 0) {
        int s = 0;
#pragma unroll
        for (int w = 0; w < NPB / 64; ++w) s += part[w];
        totals[b] = s;
    }
}

// 2) exclusive scan over bucket totals (1 small block)
__global__ __launch_bounds__(MAXB) void scan_small(
    const int* __restrict__ totals, int* __restrict__ bbase, int nbuckets) {
    __shared__ int lds[MAXB];
    int tid = threadIdx.x;
    int v = (tid < nbuckets) ? totals[tid] : 0;
    lds[tid] = v;
    __syncthreads();
    for (int off = 1; off < MAXB; off <<= 1) {
        int t = (tid >= off) ? lds[tid - off] : 0;
        __syncthreads();
        lds[tid] += t;
        __syncthreads();
    }
    if (tid < nbuckets) bbase[tid] = lds[tid] - v;   // exclusive
}

// 3) per-bucket exclusive scan of chunk counts + add bucket base (in place)
__global__ __launch_bounds__(NPB) void scan_within(
    int* __restrict__ counts, const int* __restrict__ bbase) {
    __shared__ int lds[NPB];
    int b = blockIdx.x, tid = threadIdx.x;
    int v = counts[b * NCHUNK + tid];
    lds[tid] = v;
    __syncthreads();
    for (int off = 1; off < NPB; off <<= 1) {
        int t = (tid >= off) ? lds[tid - off] : 0;
        __syncthreads();
        lds[tid] += t;
        __syncthreads();
    }
    counts[b * NCHUNK + tid] = bbase[b] + lds[tid] - v;
}

__global__ __launch_bounds__(BT) void bucket_scatter(
    const int* __restrict__ src, const int* __restrict__ dst,
    const int* __restrict__ base, unsigned* __restrict__ packed,
    int n_edges, int nbuckets, int ept) {
    __shared__ int cur[MAXB];
    for (int b = threadIdx.x; b < nbuckets; b += BT)
        cur[b] = base[b * NCHUNK + blockIdx.x];
    __syncthreads();
    int beg = blockIdx.x * ept;
    int end = min(beg + ept, n_edges);
    for (int e = beg + threadIdx.x; e < end; e += BT) {
        int s = src[e], d = dst[e];
        int slot = atomicAdd(&cur[d >> 8], 1);
        packed[slot] = (unsigned)s | ((unsigned)(d & 255) << 24);
    }
}

// ---------- per-bucket counting sort -> global CSR -------------------------

__global__ __launch_bounds__(NPB) void csr_build(
    const unsigned* __restrict__ packed, const int* __restrict__ base,
    int* __restrict__ rowptr, int* __restrict__ csr,
    int n_nodes, int nbuckets, int n_edges) {
    __shared__ int cnt[NPB];
    __shared__ int cur[NPB];
    int b = blockIdx.x, tid = threadIdx.x;
    int pBeg = base[b * NCHUNK];
    int pEnd = (b + 1 < nbuckets) ? base[(b + 1) * NCHUNK] : n_edges;
    cnt[tid] = 0;
    __syncthreads();
    for (int i = pBeg + tid; i < pEnd; i += NPB)
        atomicAdd(&cnt[packed[i] >> 24], 1);
    __syncthreads();
    int v = cnt[tid];
    cur[tid] = v;
    __syncthreads();
    for (int off = 1; off < NPB; off <<= 1) {
        int t = (tid >= off) ? cur[tid - off] : 0;
        __syncthreads();
        cur[tid] += t;
        __syncthreads();
    }
    int gbase = pBeg + cur[tid] - v;
    int n = (b << 8) + tid;
    if (n < n_nodes) rowptr[n] = gbase;
    if (b == nbuckets - 1 && tid == 0) rowptr[n_nodes] = n_edges;
    cur[tid] = gbase;
    __syncthreads();
    for (int i = pBeg + tid; i < pEnd; i += NPB) {
        unsigned p = packed[i];
        int slot = atomicAdd(&cur[p >> 24], 1);
        csr[slot] = (int)(p & 0xFFFFFF);
    }
}

// ---------- gather1: h = relu(gather_sum(xr) + xroot) ----------------------

__global__ __launch_bounds__(NT) void gather1_kernel(
    const float* __restrict__ xr, const float* xroot,
    const int* __restrict__ rowptr, const int* __restrict__ csr,
    float* h, int n_nodes) {
    int t = blockIdx.x * NT + threadIdx.x;
    int n = t >> 5, f = t & 31;
    if (n >= n_nodes) return;
    int beg = rowptr[n], end = rowptr[n + 1];
    float acc = 0.f;
    for (int i = beg; i < end; i += 16) {
        int cnt = end - i;
        int idx = f & 15;
        int e = csr[i + ((idx < cnt) ? idx : cnt - 1)];  // coalesced 16-wide
#pragma unroll
        for (int j = 0; j < 16; ++j) {
            int s = __shfl(e, j, 16);
            float v = xr[(size_t)s * H_SIZE + f];
            if (j < cnt) acc += v;
        }
    }
    h[(size_t)n * H_SIZE + f] = fmaxf(acc + xroot[(size_t)n * H_SIZE + f], 0.f);
}

// ---------- dense2: h2 = h@W2_rel^T ; hroot = h@W2_root^T + b2 (pad 16) ----

__global__ __launch_bounds__(NT) void dense2_kernel(
    const float* __restrict__ h, const float* __restrict__ W2_rel,
    const float* __restrict__ b2, const float* __restrict__ W2_root,
    float* __restrict__ h2, float* __restrict__ hroot, int n_nodes) {
    __shared__ float sWrelT[H_SIZE * 16];   // [j][c]
    __shared__ float sWrootT[H_SIZE * 16];
    __shared__ float sb[16];
    for (int i = threadIdx.x; i < H_SIZE * 16; i += NT) sWrelT[i] = sWrootT[i] = 0.f;
    __syncthreads();
    for (int i = threadIdx.x; i < N_CLASSES * H_SIZE; i += NT) {
        int c = i >> 5, j = i & 31;
        sWrelT[j * 16 + c] = W2_rel[i];
        sWrootT[j * 16 + c] = W2_root[i];
    }
    if (threadIdx.x < 16) sb[threadIdx.x] = (threadIdx.x < N_CLASSES) ? b2[threadIdx.x] : 0.f;
    __syncthreads();

    int t = blockIdx.x * NT + threadIdx.x;
    int n = t >> 4, c = t & 15;
    if (n >= n_nodes) return;
    const float* hrow = h + (size_t)n * H_SIZE;
    float ar = 0.f, ao = 0.f;
#pragma unroll
    for (int j = 0; j < H_SIZE; ++j) {
        float hv = hrow[j];
        ar += hv * sWrelT[j * 16 + c];
        ao += hv * sWrootT[j * 16 + c];
    }
    bool valid = (c < N_CLASSES);
    h2[n * 16 + c] = valid ? ar : 0.f;
    hroot[n * 16 + c] = valid ? (ao + sb[c]) : 0.f;
}

// ---------- gather2 + log-softmax + NLL ------------------------------------

__global__ __launch_bounds__(NT) void gather2_loss_kernel(
    const float* __restrict__ h2, const float* __restrict__ hroot,
    const int* __restrict__ rowptr, const int* __restrict__ csr,
    const int* __restrict__ y, float* __restrict__ loss,
    int n_nodes, float invN) {
    int t = blockIdx.x * NT + threadIdx.x;
    int n = t >> 4, c = t & 15;
    int lane = threadIdx.x & 63;
    bool active = (n < n_nodes);

    float logit = 0.f;
    int yv = 0;
    if (active) {
        int beg = rowptr[n], end = rowptr[n + 1];
        float acc = 0.f;
        for (int i = beg; i < end; i += 16) {
            int cnt = end - i;
            int e = csr[i + ((c < cnt) ? c : cnt - 1)];
#pragma unroll
            for (int j = 0; j < 16; ++j) {
                int s = __shfl(e, j, 16);
                float v = h2[(size_t)s * 16 + c];
                if (j < cnt) acc += v;
            }
        }
        logit = acc + hroot[(size_t)n * 16 + c];
        yv = y[n];
    }
    float lm = (active && c < N_CLASSES) ? logit : -INFINITY;
#pragma unroll
    for (int m = 1; m < 16; m <<= 1) lm = fmaxf(lm, __shfl_xor(lm, m, 64));
    float e = (active && c < N_CLASSES) ? expf(logit - lm) : 0.f;
#pragma unroll
    for (int m = 1; m < 16; m <<= 1) e += __shfl_xor(e, m, 64);
    float ly = __shfl(logit, (lane & ~15) + yv, 64);
    float contrib = (active && c == 0) ? (lm + logf(e) - ly) * invN : 0.f;

#pragma unroll
    for (int o = 32; o > 0; o >>= 1) contrib += __shfl_down(contrib, o, 64);
    __shared__ float part[NT / 64];
    if (lane == 0) part[threadIdx.x >> 6] = contrib;
    __syncthreads();
    if (threadIdx.x == 0) {
        float v = 0.f;
#pragma unroll
        for (int w = 0; w < NT / 64; ++w) v += part[w];
        atomicAdd(loss, v);
    }
}

// ---------------------------------------------------------------------------

extern "C" void kernel_launch(void* const* d_in, const int* in_sizes, int n_in,
                              void* d_out, int out_size, void* d_ws, size_t ws_size,
                              hipStream_t stream) {
    const float* x       = (const float*)d_in[0];
    const int*   ei      = (const int*)d_in[1];
    const int*   y       = (const int*)d_in[2];
    const float* W1_rel  = (const float*)d_in[3];
    const float* b1_rel  = (const float*)d_in[4];
    const float* W1_root = (const float*)d_in[5];
    const float* W2_rel  = (const float*)d_in[6];
    const float* b2_rel  = (const float*)d_in[7];
    const float* W2_root = (const float*)d_in[8];
    float* loss = (float*)d_out;

    const int n_nodes = in_sizes[0] / D_FEAT;
    const int n_edges = in_sizes[1] / 2;
    const int* src = ei;
    const int* dst = ei + n_edges;

    const int nbuckets = (n_nodes + NPB - 1) / NPB;
    const int M = nbuckets * NCHUNK;
    const int ept = (n_edges + NCHUNK - 1) / NCHUNK;

    size_t off = 0;
    auto alloc = [&](size_t bytes) {
        void* p = (char*)d_ws + off;
        off = (off + bytes + 255) & ~(size_t)255;
        return p;
    };
    int*      counts = (int*)alloc((size_t)(M + 1) * 4);
    int*      totals = (int*)alloc((size_t)MAXB * 4);
    int*      bbase  = (int*)alloc((size_t)MAXB * 4);
    unsigned* packed = (unsigned*)alloc((size_t)n_edges * 4);
    int*      rowptr = (int*)alloc((size_t)(n_nodes + 1) * 4);
    int*      csr    = (int*)alloc((size_t)n_edges * 4);
    float*    xr     = (float*)alloc((size_t)n_nodes * H_SIZE * 4);
    float*    xroot  = (float*)alloc((size_t)n_nodes * H_SIZE * 4);  // h aliases
    float*    h2     = (float*)alloc((size_t)n_nodes * 16 * 4);
    float*    hroot  = (float*)alloc((size_t)n_nodes * 16 * 4);
    float*    h      = xroot;

    // dense pre-transform
    dense1_kernel<<<(n_nodes * H_SIZE + NT - 1) / NT, NT, 0, stream>>>(
        x, W1_rel, b1_rel, W1_root, xr, xroot, n_nodes);

    // bucket build -> packed -> CSR
    bucket_count<<<NCHUNK, BT, 0, stream>>>(dst, counts, n_edges, nbuckets, ept);
    bucket_totals<<<nbuckets, NPB, 0, stream>>>(counts, totals);
    scan_small<<<1, MAXB, 0, stream>>>(totals, bbase, nbuckets);
    scan_within<<<nbuckets, NPB, 0, stream>>>(counts, bbase);
    bucket_scatter<<<NCHUNK, BT, 0, stream>>>(src, dst, counts, packed,
                                              n_edges, nbuckets, ept);
    csr_build<<<nbuckets, NPB, 0, stream>>>(packed, counts, rowptr, csr,
                                            n_nodes, nbuckets, n_edges);

    // layer 1
    gather1_kernel<<<(n_nodes * H_SIZE + NT - 1) / NT, NT, 0, stream>>>(
        xr, xroot, rowptr, csr, h, n_nodes);

    // layer 2 + loss
    dense2_kernel<<<(n_nodes * 16 + NT - 1) / NT, NT, 0, stream>>>(
        h, W2_rel, b2_rel, W2_root, h2, hroot, n_nodes);
    hipMemsetAsync(loss, 0, sizeof(float), stream);
    gather2_loss_kernel<<<(n_nodes * 16 + NT - 1) / NT, NT, 0, stream>>>(
        h2, hroot, rowptr, csr, y, loss, n_nodes, 1.f / (float)n_nodes);
}

// Round 6
// 340.947 us; speedup vs baseline: 3.9667x; 1.1853x over previous
//
#include <hip/hip_runtime.h>

#define D_FEAT 64
#define H_SIZE 32
#define N_CLASSES 10
#define NPB 256          // nodes per bucket (bucket = dst >> 8)
#define MAXB 512
#define NCHUNK 256       // edge chunks for count/scatter passes
#define BT 1024
#define NT 256
#define D1N 64           // nodes per dense1 block

// ---------- dense1: xr = x@W1_rel^T ; xroot = x@W1_root^T + b1 -------------
// LDS: weights [f][k] stride 33 (conflict-free write+read), x staged float4.

__global__ __launch_bounds__(NT) void dense1_kernel(
    const float* __restrict__ x, const float* __restrict__ W1_rel,
    const float* __restrict__ b1, const float* __restrict__ W1_root,
    float* __restrict__ xr, float* __restrict__ xroot, int n_nodes) {
    __shared__ float sWrel[D_FEAT * 33];
    __shared__ float sWroot[D_FEAT * 33];
    __shared__ float sx[D1N * D_FEAT];
    __shared__ float sb[H_SIZE];
    int tid = threadIdx.x;
    for (int i = tid; i < H_SIZE * D_FEAT; i += NT) {
        int k = i >> 6, f = i & 63;          // W[k][f] row-major in
        sWrel[f * 33 + k] = W1_rel[i];       // bank (f+k)%32 -> conflict-free
        sWroot[f * 33 + k] = W1_root[i];
    }
    if (tid < H_SIZE) sb[tid] = b1[tid];

    int nbase = blockIdx.x * D1N;
    int nvalid = min(D1N, n_nodes - nbase);
    const float4* x4 = (const float4*)(x + (size_t)nbase * D_FEAT);
    float4* sx4 = (float4*)sx;
    for (int i = tid; i < nvalid * (D_FEAT / 4); i += NT) sx4[i] = x4[i];
    __syncthreads();

    int k = tid & 31, g = tid >> 5;          // 8 node-groups of 8
#pragma unroll
    for (int j = 0; j < 2; ++j) {
        int nl = g * 8 + j * 4;
        if (nl >= nvalid) break;
        int last = nvalid - 1;
        const float* r0 = sx + min(nl + 0, last) * D_FEAT;
        const float* r1 = sx + min(nl + 1, last) * D_FEAT;
        const float* r2 = sx + min(nl + 2, last) * D_FEAT;
        const float* r3 = sx + min(nl + 3, last) * D_FEAT;
        float a0 = 0.f, a1 = 0.f, a2 = 0.f, a3 = 0.f;
        float o0 = 0.f, o1 = 0.f, o2 = 0.f, o3 = 0.f;
#pragma unroll
        for (int f = 0; f < D_FEAT; ++f) {
            float wr = sWrel[f * 33 + k];
            float wo = sWroot[f * 33 + k];
            float v0 = r0[f], v1 = r1[f], v2 = r2[f], v3 = r3[f];
            a0 += v0 * wr; a1 += v1 * wr; a2 += v2 * wr; a3 += v3 * wr;
            o0 += v0 * wo; o1 += v1 * wo; o2 += v2 * wo; o3 += v3 * wo;
        }
        float bk = sb[k];
#pragma unroll
        for (int u = 0; u < 4; ++u) {
            int nn = nl + u;
            if (nn < nvalid) {
                size_t idx = (size_t)(nbase + nn) * H_SIZE + k;
                float ar = (u == 0) ? a0 : (u == 1) ? a1 : (u == 2) ? a2 : a3;
                float ao = (u == 0) ? o0 : (u == 1) ? o1 : (u == 2) ? o2 : o3;
                xr[idx] = ar;
                xroot[idx] = ao + bk;
            }
        }
    }
}

// ---------- bucket count -> hierarchical scan -> scatter -------------------

__global__ __launch_bounds__(BT) void bucket_count(
    const int* __restrict__ dst, int* __restrict__ counts,
    int n_edges, int nbuckets, int ept) {
    __shared__ int hist[MAXB];
    for (int i = threadIdx.x; i < nbuckets; i += BT) hist[i] = 0;
    __syncthreads();
    int beg = blockIdx.x * ept;
    int end = min(beg + ept, n_edges);
    for (int e = beg + threadIdx.x; e < end; e += BT)
        atomicAdd(&hist[dst[e] >> 8], 1);
    __syncthreads();
    for (int b = threadIdx.x; b < nbuckets; b += BT)
        counts[b * NCHUNK + blockIdx.x] = hist[b];
}

__global__ __launch_bounds__(NPB) void bucket_totals(
    const int* __restrict__ counts, int* __restrict__ totals) {
    int b = blockIdx.x, tid = threadIdx.x;
    int v = counts[b * NCHUNK + tid];
#pragma unroll
    for (int o = 32; o > 0; o >>= 1) v += __shfl_down(v, o, 64);
    __shared__ int part[NPB / 64];
    if ((tid & 63) == 0) part[tid >> 6] = v;
    __syncthreads();
    if (tid == 0) {
        int s = 0;
#pragma unroll
        for (int w = 0; w < NPB / 64; ++w) s += part[w];
        totals[b] = s;
    }
}

__global__ __launch_bounds__(MAXB) void scan_small(
    const int* __restrict__ totals, int* __restrict__ bbase, int nbuckets) {
    __shared__ int lds[MAXB];
    int tid = threadIdx.x;
    int v = (tid < nbuckets) ? totals[tid] : 0;
    lds[tid] = v;
    __syncthreads();
    for (int off = 1; off < MAXB; off <<= 1) {
        int t = (tid >= off) ? lds[tid - off] : 0;
        __syncthreads();
        lds[tid] += t;
        __syncthreads();
    }
    if (tid < nbuckets) bbase[tid] = lds[tid] - v;
}

__global__ __launch_bounds__(NPB) void scan_within(
    int* __restrict__ counts, const int* __restrict__ bbase) {
    __shared__ int lds[NPB];
    int b = blockIdx.x, tid = threadIdx.x;
    int v = counts[b * NCHUNK + tid];
    lds[tid] = v;
    __syncthreads();
    for (int off = 1; off < NPB; off <<= 1) {
        int t = (tid >= off) ? lds[tid - off] : 0;
        __syncthreads();
        lds[tid] += t;
        __syncthreads();
    }
    counts[b * NCHUNK + tid] = bbase[b] + lds[tid] - v;
}

__global__ __launch_bounds__(BT) void bucket_scatter(
    const int* __restrict__ src, const int* __restrict__ dst,
    const int* __restrict__ base, unsigned* __restrict__ packed,
    int n_edges, int nbuckets, int ept) {
    __shared__ int cur[MAXB];
    for (int b = threadIdx.x; b < nbuckets; b += BT)
        cur[b] = base[b * NCHUNK + blockIdx.x];
    __syncthreads();
    int beg = blockIdx.x * ept;
    int end = min(beg + ept, n_edges);
    for (int e = beg + threadIdx.x; e < end; e += BT) {
        int s = src[e], d = dst[e];
        int slot = atomicAdd(&cur[d >> 8], 1);
        packed[slot] = (unsigned)s | ((unsigned)(d & 255) << 24);
    }
}

// ---------- per-bucket counting sort -> global CSR -------------------------

__global__ __launch_bounds__(NPB) void csr_build(
    const unsigned* __restrict__ packed, const int* __restrict__ base,
    int* __restrict__ rowptr, int* __restrict__ csr,
    int n_nodes, int nbuckets, int n_edges) {
    __shared__ int cnt[NPB];
    __shared__ int cur[NPB];
    int b = blockIdx.x, tid = threadIdx.x;
    int pBeg = base[b * NCHUNK];
    int pEnd = (b + 1 < nbuckets) ? base[(b + 1) * NCHUNK] : n_edges;
    cnt[tid] = 0;
    __syncthreads();
    for (int i = pBeg + tid; i < pEnd; i += NPB)
        atomicAdd(&cnt[packed[i] >> 24], 1);
    __syncthreads();
    int v = cnt[tid];
    cur[tid] = v;
    __syncthreads();
    for (int off = 1; off < NPB; off <<= 1) {
        int t = (tid >= off) ? cur[tid - off] : 0;
        __syncthreads();
        cur[tid] += t;
        __syncthreads();
    }
    int gbase = pBeg + cur[tid] - v;
    int n = (b << 8) + tid;
    if (n < n_nodes) rowptr[n] = gbase;
    if (b == nbuckets - 1 && tid == 0) rowptr[n_nodes] = n_edges;
    cur[tid] = gbase;
    __syncthreads();
    for (int i = pBeg + tid; i < pEnd; i += NPB) {
        unsigned p = packed[i];
        int slot = atomicAdd(&cur[p >> 24], 1);
        csr[slot] = (int)(p & 0xFFFFFF);
    }
}

// ---------- gather1: h = relu(gather_sum(xr) + xroot) ----------------------

__global__ __launch_bounds__(NT) void gather1_kernel(
    const float* __restrict__ xr, const float* xroot,
    const int* __restrict__ rowptr, const int* __restrict__ csr,
    float* h, int n_nodes) {
    int t = blockIdx.x * NT + threadIdx.x;
    int n = t >> 5, f = t & 31;
    if (n >= n_nodes) return;
    int beg = rowptr[n], end = rowptr[n + 1];
    float acc = 0.f;
    for (int i = beg; i < end; i += 16) {
        int cnt = end - i;
        int idx = f & 15;
        int e = csr[i + ((idx < cnt) ? idx : cnt - 1)];  // coalesced 16-wide
#pragma unroll
        for (int j = 0; j < 16; ++j) {
            int s = __shfl(e, j, 16);
            float v = xr[(size_t)s * H_SIZE + f];
            if (j < cnt) acc += v;
        }
    }
    h[(size_t)n * H_SIZE + f] = fmaxf(acc + xroot[(size_t)n * H_SIZE + f], 0.f);
}

// ---------- dense2: h2 = h@W2_rel^T ; hroot = h@W2_root^T + b2 (pad 16) ----

__global__ __launch_bounds__(NT) void dense2_kernel(
    const float* __restrict__ h, const float* __restrict__ W2_rel,
    const float* __restrict__ b2, const float* __restrict__ W2_root,
    float* __restrict__ h2, float* __restrict__ hroot, int n_nodes) {
    __shared__ float sWrelT[H_SIZE * 17];   // [j][c] stride 17: conflict-free
    __shared__ float sWrootT[H_SIZE * 17];
    __shared__ float sb[16];
    for (int i = threadIdx.x; i < H_SIZE * 17; i += NT) sWrelT[i] = sWrootT[i] = 0.f;
    __syncthreads();
    for (int i = threadIdx.x; i < N_CLASSES * H_SIZE; i += NT) {
        int c = i >> 5, j = i & 31;
        sWrelT[j * 17 + c] = W2_rel[i];
        sWrootT[j * 17 + c] = W2_root[i];
    }
    if (threadIdx.x < 16) sb[threadIdx.x] = (threadIdx.x < N_CLASSES) ? b2[threadIdx.x] : 0.f;
    __syncthreads();

    int t = blockIdx.x * NT + threadIdx.x;
    int n = t >> 4, c = t & 15;
    if (n >= n_nodes) return;
    const float* hrow = h + (size_t)n * H_SIZE;
    float ar = 0.f, ao = 0.f;
#pragma unroll
    for (int j = 0; j < H_SIZE; ++j) {
        float hv = hrow[j];
        ar += hv * sWrelT[j * 17 + c];
        ao += hv * sWrootT[j * 17 + c];
    }
    bool valid = (c < N_CLASSES);
    h2[n * 16 + c] = valid ? ar : 0.f;
    hroot[n * 16 + c] = valid ? (ao + sb[c]) : 0.f;
}

// ---------- gather2 + log-softmax + NLL ------------------------------------

__global__ __launch_bounds__(NT) void gather2_loss_kernel(
    const float* __restrict__ h2, const float* __restrict__ hroot,
    const int* __restrict__ rowptr, const int* __restrict__ csr,
    const int* __restrict__ y, float* __restrict__ loss,
    int n_nodes, float invN) {
    int t = blockIdx.x * NT + threadIdx.x;
    int n = t >> 4, c = t & 15;
    int lane = threadIdx.x & 63;
    bool active = (n < n_nodes);

    float logit = 0.f;
    int yv = 0;
    if (active) {
        int beg = rowptr[n], end = rowptr[n + 1];
        float acc = 0.f;
        for (int i = beg; i < end; i += 16) {
            int cnt = end - i;
            int e = csr[i + ((c < cnt) ? c : cnt - 1)];
#pragma unroll
            for (int j = 0; j < 16; ++j) {
                int s = __shfl(e, j, 16);
                float v = h2[(size_t)s * 16 + c];
                if (j < cnt) acc += v;
            }
        }
        logit = acc + hroot[(size_t)n * 16 + c];
        yv = y[n];
    }
    float lm = (active && c < N_CLASSES) ? logit : -INFINITY;
#pragma unroll
    for (int m = 1; m < 16; m <<= 1) lm = fmaxf(lm, __shfl_xor(lm, m, 64));
    float e = (active && c < N_CLASSES) ? expf(logit - lm) : 0.f;
#pragma unroll
    for (int m = 1; m < 16; m <<= 1) e += __shfl_xor(e, m, 64);
    float ly = __shfl(logit, (lane & ~15) + yv, 64);
    float contrib = (active && c == 0) ? (lm + logf(e) - ly) * invN : 0.f;

#pragma unroll
    for (int o = 32; o > 0; o >>= 1) contrib += __shfl_down(contrib, o, 64);
    __shared__ float part[NT / 64];
    if (lane == 0) part[threadIdx.x >> 6] = contrib;
    __syncthreads();
    if (threadIdx.x == 0) {
        float v = 0.f;
#pragma unroll
        for (int w = 0; w < NT / 64; ++w) v += part[w];
        atomicAdd(loss, v);
    }
}

// ---------------------------------------------------------------------------

extern "C" void kernel_launch(void* const* d_in, const int* in_sizes, int n_in,
                              void* d_out, int out_size, void* d_ws, size_t ws_size,
                              hipStream_t stream) {
    const float* x       = (const float*)d_in[0];
    const int*   ei      = (const int*)d_in[1];
    const int*   y       = (const int*)d_in[2];
    const float* W1_rel  = (const float*)d_in[3];
    const float* b1_rel  = (const float*)d_in[4];
    const float* W1_root = (const float*)d_in[5];
    const float* W2_rel  = (const float*)d_in[6];
    const float* b2_rel  = (const float*)d_in[7];
    const float* W2_root = (const float*)d_in[8];
    float* loss = (float*)d_out;

    const int n_nodes = in_sizes[0] / D_FEAT;
    const int n_edges = in_sizes[1] / 2;
    const int* src = ei;
    const int* dst = ei + n_edges;

    const int nbuckets = (n_nodes + NPB - 1) / NPB;
    const int M = nbuckets * NCHUNK;
    const int ept = (n_edges + NCHUNK - 1) / NCHUNK;

    size_t off = 0;
    auto alloc = [&](size_t bytes) {
        void* p = (char*)d_ws + off;
        off = (off + bytes + 255) & ~(size_t)255;
        return p;
    };
    int*      counts = (int*)alloc((size_t)(M + 1) * 4);
    int*      totals = (int*)alloc((size_t)MAXB * 4);
    int*      bbase  = (int*)alloc((size_t)MAXB * 4);
    unsigned* packed = (unsigned*)alloc((size_t)n_edges * 4);
    int*      rowptr = (int*)alloc((size_t)(n_nodes + 1) * 4);
    int*      csr    = (int*)alloc((size_t)n_edges * 4);
    float*    xr     = (float*)alloc((size_t)n_nodes * H_SIZE * 4);
    float*    xroot  = (float*)alloc((size_t)n_nodes * H_SIZE * 4);  // h aliases
    float*    h2     = (float*)alloc((size_t)n_nodes * 16 * 4);
    float*    hroot  = (float*)alloc((size_t)n_nodes * 16 * 4);
    float*    h      = xroot;

    // dense pre-transform
    dense1_kernel<<<(n_nodes + D1N - 1) / D1N, NT, 0, stream>>>(
        x, W1_rel, b1_rel, W1_root, xr, xroot, n_nodes);

    // bucket build -> packed -> CSR
    bucket_count<<<NCHUNK, BT, 0, stream>>>(dst, counts, n_edges, nbuckets, ept);
    bucket_totals<<<nbuckets, NPB, 0, stream>>>(counts, totals);
    scan_small<<<1, MAXB, 0, stream>>>(totals, bbase, nbuckets);
    scan_within<<<nbuckets, NPB, 0, stream>>>(counts, bbase);
    bucket_scatter<<<NCHUNK, BT, 0, stream>>>(src, dst, counts, packed,
                                              n_edges, nbuckets, ept);
    csr_build<<<nbuckets, NPB, 0, stream>>>(packed, counts, rowptr, csr,
                                            n_nodes, nbuckets, n_edges);

    // layer 1
    gather1_kernel<<<(n_nodes * H_SIZE + NT - 1) / NT, NT, 0, stream>>>(
        xr, xroot, rowptr, csr, h, n_nodes);

    // layer 2 + loss
    dense2_kernel<<<(n_nodes * 16 + NT - 1) / NT, NT, 0, stream>>>(
        h, W2_rel, b2_rel, W2_root, h2, hroot, n_nodes);
    hipMemsetAsync(loss, 0, sizeof(float), stream);
    gather2_loss_kernel<<<(n_nodes * 16 + NT - 1) / NT, NT, 0, stream>>>(
        h2, hroot, rowptr, csr, y, loss, n_nodes, 1.f / (float)n_nodes);
}

// Round 7
// 252.482 us; speedup vs baseline: 5.3565x; 1.3504x over previous
//
#include <hip/hip_runtime.h>
#include <hip/hip_bf16.h>

#define D_FEAT 64
#define H_SIZE 32
#define N_CLASSES 10
#define NPB 256          // nodes per bucket (bucket = dst >> 8)
#define MAXB 512
#define NCHUNK 256       // edge chunks for count/scatter passes
#define BT 1024
#define NT 256
#define D1N 64           // nodes per dense1 block

// ---------- dense1: xr(bf16) = x@W1_rel^T ; xroot = x@W1_root^T + b1 -------

__global__ __launch_bounds__(NT) void dense1_kernel(
    const float* __restrict__ x, const float* __restrict__ W1_rel,
    const float* __restrict__ b1, const float* __restrict__ W1_root,
    __hip_bfloat16* __restrict__ xr, float* __restrict__ xroot, int n_nodes) {
    __shared__ float sWrel[D_FEAT * 33];
    __shared__ float sWroot[D_FEAT * 33];
    __shared__ float sx[D1N * D_FEAT];
    __shared__ float sb[H_SIZE];
    int tid = threadIdx.x;
    for (int i = tid; i < H_SIZE * D_FEAT; i += NT) {
        int k = i >> 6, f = i & 63;          // W[k][f] row-major in
        sWrel[f * 33 + k] = W1_rel[i];       // bank (f+k)%32 -> conflict-free
        sWroot[f * 33 + k] = W1_root[i];
    }
    if (tid < H_SIZE) sb[tid] = b1[tid];

    int nbase = blockIdx.x * D1N;
    int nvalid = min(D1N, n_nodes - nbase);
    const float4* x4 = (const float4*)(x + (size_t)nbase * D_FEAT);
    float4* sx4 = (float4*)sx;
    for (int i = tid; i < nvalid * (D_FEAT / 4); i += NT) sx4[i] = x4[i];
    __syncthreads();

    int k = tid & 31, g = tid >> 5;          // 8 node-groups of 8
#pragma unroll
    for (int j = 0; j < 2; ++j) {
        int nl = g * 8 + j * 4;
        if (nl >= nvalid) break;
        int last = nvalid - 1;
        const float* r0 = sx + min(nl + 0, last) * D_FEAT;
        const float* r1 = sx + min(nl + 1, last) * D_FEAT;
        const float* r2 = sx + min(nl + 2, last) * D_FEAT;
        const float* r3 = sx + min(nl + 3, last) * D_FEAT;
        float a0 = 0.f, a1 = 0.f, a2 = 0.f, a3 = 0.f;
        float o0 = 0.f, o1 = 0.f, o2 = 0.f, o3 = 0.f;
#pragma unroll
        for (int f = 0; f < D_FEAT; ++f) {
            float wr = sWrel[f * 33 + k];
            float wo = sWroot[f * 33 + k];
            float v0 = r0[f], v1 = r1[f], v2 = r2[f], v3 = r3[f];
            a0 += v0 * wr; a1 += v1 * wr; a2 += v2 * wr; a3 += v3 * wr;
            o0 += v0 * wo; o1 += v1 * wo; o2 += v2 * wo; o3 += v3 * wo;
        }
        float bk = sb[k];
#pragma unroll
        for (int u = 0; u < 4; ++u) {
            int nn = nl + u;
            if (nn < nvalid) {
                size_t idx = (size_t)(nbase + nn) * H_SIZE + k;
                float ar = (u == 0) ? a0 : (u == 1) ? a1 : (u == 2) ? a2 : a3;
                float ao = (u == 0) ? o0 : (u == 1) ? o1 : (u == 2) ? o2 : o3;
                xr[idx] = __float2bfloat16(ar);
                xroot[idx] = ao + bk;
            }
        }
    }
}

// ---------- bucket count -> hierarchical scan -> scatter -------------------

__global__ __launch_bounds__(BT) void bucket_count(
    const int* __restrict__ dst, int* __restrict__ counts,
    int n_edges, int nbuckets, int ept) {
    __shared__ int hist[MAXB];
    for (int i = threadIdx.x; i < nbuckets; i += BT) hist[i] = 0;
    __syncthreads();
    int beg = blockIdx.x * ept;
    int end = min(beg + ept, n_edges);
    for (int e = beg + threadIdx.x; e < end; e += BT)
        atomicAdd(&hist[dst[e] >> 8], 1);
    __syncthreads();
    for (int b = threadIdx.x; b < nbuckets; b += BT)
        counts[b * NCHUNK + blockIdx.x] = hist[b];
}

__global__ __launch_bounds__(NPB) void bucket_totals(
    const int* __restrict__ counts, int* __restrict__ totals) {
    int b = blockIdx.x, tid = threadIdx.x;
    int v = counts[b * NCHUNK + tid];
#pragma unroll
    for (int o = 32; o > 0; o >>= 1) v += __shfl_down(v, o, 64);
    __shared__ int part[NPB / 64];
    if ((tid & 63) == 0) part[tid >> 6] = v;
    __syncthreads();
    if (tid == 0) {
        int s = 0;
#pragma unroll
        for (int w = 0; w < NPB / 64; ++w) s += part[w];
        totals[b] = s;
    }
}

__global__ __launch_bounds__(MAXB) void scan_small(
    const int* __restrict__ totals, int* __restrict__ bbase, int nbuckets) {
    __shared__ int lds[MAXB];
    int tid = threadIdx.x;
    int v = (tid < nbuckets) ? totals[tid] : 0;
    lds[tid] = v;
    __syncthreads();
    for (int off = 1; off < MAXB; off <<= 1) {
        int t = (tid >= off) ? lds[tid - off] : 0;
        __syncthreads();
        lds[tid] += t;
        __syncthreads();
    }
    if (tid < nbuckets) bbase[tid] = lds[tid] - v;
}

__global__ __launch_bounds__(NPB) void scan_within(
    int* __restrict__ counts, const int* __restrict__ bbase) {
    __shared__ int lds[NPB];
    int b = blockIdx.x, tid = threadIdx.x;
    int v = counts[b * NCHUNK + tid];
    lds[tid] = v;
    __syncthreads();
    for (int off = 1; off < NPB; off <<= 1) {
        int t = (tid >= off) ? lds[tid - off] : 0;
        __syncthreads();
        lds[tid] += t;
        __syncthreads();
    }
    counts[b * NCHUNK + tid] = bbase[b] + lds[tid] - v;
}

__global__ __launch_bounds__(BT) void bucket_scatter(
    const int* __restrict__ src, const int* __restrict__ dst,
    const int* __restrict__ base, unsigned* __restrict__ packed,
    int n_edges, int nbuckets, int ept) {
    __shared__ int cur[MAXB];
    for (int b = threadIdx.x; b < nbuckets; b += BT)
        cur[b] = base[b * NCHUNK + blockIdx.x];
    __syncthreads();
    int beg = blockIdx.x * ept;
    int end = min(beg + ept, n_edges);
    for (int e = beg + threadIdx.x; e < end; e += BT) {
        int s = src[e], d = dst[e];
        int slot = atomicAdd(&cur[d >> 8], 1);
        packed[slot] = (unsigned)s | ((unsigned)(d & 255) << 24);
    }
}

// ---------- per-bucket counting sort -> global CSR -------------------------

__global__ __launch_bounds__(NPB) void csr_build(
    const unsigned* __restrict__ packed, const int* __restrict__ base,
    int* __restrict__ rowptr, int* __restrict__ csr,
    int n_nodes, int nbuckets, int n_edges) {
    __shared__ int cnt[NPB];
    __shared__ int cur[NPB];
    int b = blockIdx.x, tid = threadIdx.x;
    int pBeg = base[b * NCHUNK];
    int pEnd = (b + 1 < nbuckets) ? base[(b + 1) * NCHUNK] : n_edges;
    cnt[tid] = 0;
    __syncthreads();
    for (int i = pBeg + tid; i < pEnd; i += NPB)
        atomicAdd(&cnt[packed[i] >> 24], 1);
    __syncthreads();
    int v = cnt[tid];
    cur[tid] = v;
    __syncthreads();
    for (int off = 1; off < NPB; off <<= 1) {
        int t = (tid >= off) ? cur[tid - off] : 0;
        __syncthreads();
        cur[tid] += t;
        __syncthreads();
    }
    int gbase = pBeg + cur[tid] - v;
    int n = (b << 8) + tid;
    if (n < n_nodes) rowptr[n] = gbase;
    if (b == nbuckets - 1 && tid == 0) rowptr[n_nodes] = n_edges;
    cur[tid] = gbase;
    __syncthreads();
    for (int i = pBeg + tid; i < pEnd; i += NPB) {
        unsigned p = packed[i];
        int slot = atomicAdd(&cur[p >> 24], 1);
        csr[slot] = (int)(p & 0xFFFFFF);
    }
}

// ---------- gather1: h = relu(gather_sum(xr_bf16) + xroot) -----------------

__global__ __launch_bounds__(NT) void gather1_kernel(
    const __hip_bfloat16* __restrict__ xr, const float* xroot,
    const int* __restrict__ rowptr, const int* __restrict__ csr,
    float* h, int n_nodes) {
    int t = blockIdx.x * NT + threadIdx.x;
    int n = t >> 5, f = t & 31;
    if (n >= n_nodes) return;
    int beg = rowptr[n], end = rowptr[n + 1];
    float acc = 0.f;
    for (int i = beg; i < end; i += 16) {
        int cnt = end - i;
        int idx = f & 15;
        int e = csr[i + ((idx < cnt) ? idx : cnt - 1)];  // coalesced 16-wide
#pragma unroll
        for (int j = 0; j < 16; ++j) {
            int s = __shfl(e, j, 16);
            float v = __bfloat162float(xr[(size_t)s * H_SIZE + f]);
            if (j < cnt) acc += v;
        }
    }
    h[(size_t)n * H_SIZE + f] = fmaxf(acc + xroot[(size_t)n * H_SIZE + f], 0.f);
}

// ---------- dense2: h2(bf16) = h@W2_rel^T ; hroot = h@W2_root^T + b2 -------

__global__ __launch_bounds__(NT) void dense2_kernel(
    const float* __restrict__ h, const float* __restrict__ W2_rel,
    const float* __restrict__ b2, const float* __restrict__ W2_root,
    __hip_bfloat16* __restrict__ h2, float* __restrict__ hroot, int n_nodes) {
    __shared__ float sWrelT[H_SIZE * 17];   // [j][c] stride 17: conflict-free
    __shared__ float sWrootT[H_SIZE * 17];
    __shared__ float sb[16];
    for (int i = threadIdx.x; i < H_SIZE * 17; i += NT) sWrelT[i] = sWrootT[i] = 0.f;
    __syncthreads();
    for (int i = threadIdx.x; i < N_CLASSES * H_SIZE; i += NT) {
        int c = i >> 5, j = i & 31;
        sWrelT[j * 17 + c] = W2_rel[i];
        sWrootT[j * 17 + c] = W2_root[i];
    }
    if (threadIdx.x < 16) sb[threadIdx.x] = (threadIdx.x < N_CLASSES) ? b2[threadIdx.x] : 0.f;
    __syncthreads();

    int t = blockIdx.x * NT + threadIdx.x;
    int n = t >> 4, c = t & 15;
    if (n >= n_nodes) return;
    const float* hrow = h + (size_t)n * H_SIZE;
    float ar = 0.f, ao = 0.f;
#pragma unroll
    for (int j = 0; j < H_SIZE; ++j) {
        float hv = hrow[j];
        ar += hv * sWrelT[j * 17 + c];
        ao += hv * sWrootT[j * 17 + c];
    }
    bool valid = (c < N_CLASSES);
    h2[n * 16 + c] = __float2bfloat16(valid ? ar : 0.f);
    hroot[n * 16 + c] = valid ? (ao + sb[c]) : 0.f;
}

// ---------- gather2 + log-softmax + NLL ------------------------------------

__global__ __launch_bounds__(NT) void gather2_loss_kernel(
    const __hip_bfloat16* __restrict__ h2, const float* __restrict__ hroot,
    const int* __restrict__ rowptr, const int* __restrict__ csr,
    const int* __restrict__ y, float* __restrict__ loss,
    int n_nodes, float invN) {
    int t = blockIdx.x * NT + threadIdx.x;
    int n = t >> 4, c = t & 15;
    int lane = threadIdx.x & 63;
    bool active = (n < n_nodes);

    float logit = 0.f;
    int yv = 0;
    if (active) {
        int beg = rowptr[n], end = rowptr[n + 1];
        float acc = 0.f;
        for (int i = beg; i < end; i += 16) {
            int cnt = end - i;
            int e = csr[i + ((c < cnt) ? c : cnt - 1)];
#pragma unroll
            for (int j = 0; j < 16; ++j) {
                int s = __shfl(e, j, 16);
                float v = __bfloat162float(h2[(size_t)s * 16 + c]);
                if (j < cnt) acc += v;
            }
        }
        logit = acc + hroot[(size_t)n * 16 + c];
        yv = y[n];
    }
    float lm = (active && c < N_CLASSES) ? logit : -INFINITY;
#pragma unroll
    for (int m = 1; m < 16; m <<= 1) lm = fmaxf(lm, __shfl_xor(lm, m, 64));
    float e = (active && c < N_CLASSES) ? expf(logit - lm) : 0.f;
#pragma unroll
    for (int m = 1; m < 16; m <<= 1) e += __shfl_xor(e, m, 64);
    float ly = __shfl(logit, (lane & ~15) + yv, 64);
    float contrib = (active && c == 0) ? (lm + logf(e) - ly) * invN : 0.f;

#pragma unroll
    for (int o = 32; o > 0; o >>= 1) contrib += __shfl_down(contrib, o, 64);
    __shared__ float part[NT / 64];
    if (lane == 0) part[threadIdx.x >> 6] = contrib;
    __syncthreads();
    if (threadIdx.x == 0) {
        float v = 0.f;
#pragma unroll
        for (int w = 0; w < NT / 64; ++w) v += part[w];
        atomicAdd(loss, v);
    }
}

// ---------------------------------------------------------------------------

extern "C" void kernel_launch(void* const* d_in, const int* in_sizes, int n_in,
                              void* d_out, int out_size, void* d_ws, size_t ws_size,
                              hipStream_t stream) {
    const float* x       = (const float*)d_in[0];
    const int*   ei      = (const int*)d_in[1];
    const int*   y       = (const int*)d_in[2];
    const float* W1_rel  = (const float*)d_in[3];
    const float* b1_rel  = (const float*)d_in[4];
    const float* W1_root = (const float*)d_in[5];
    const float* W2_rel  = (const float*)d_in[6];
    const float* b2_rel  = (const float*)d_in[7];
    const float* W2_root = (const float*)d_in[8];
    float* loss = (float*)d_out;

    const int n_nodes = in_sizes[0] / D_FEAT;
    const int n_edges = in_sizes[1] / 2;
    const int* src = ei;
    const int* dst = ei + n_edges;

    const int nbuckets = (n_nodes + NPB - 1) / NPB;
    const int M = nbuckets * NCHUNK;
    const int ept = (n_edges + NCHUNK - 1) / NCHUNK;

    size_t off = 0;
    auto alloc = [&](size_t bytes) {
        void* p = (char*)d_ws + off;
        off = (off + bytes + 255) & ~(size_t)255;
        return p;
    };
    int*            counts = (int*)alloc((size_t)(M + 1) * 4);
    int*            totals = (int*)alloc((size_t)MAXB * 4);
    int*            bbase  = (int*)alloc((size_t)MAXB * 4);
    unsigned*       packed = (unsigned*)alloc((size_t)n_edges * 4);
    int*            rowptr = (int*)alloc((size_t)(n_nodes + 1) * 4);
    int*            csr    = (int*)alloc((size_t)n_edges * 4);
    __hip_bfloat16* xr     = (__hip_bfloat16*)alloc((size_t)n_nodes * H_SIZE * 2);
    float*          xroot  = (float*)alloc((size_t)n_nodes * H_SIZE * 4);  // h aliases
    __hip_bfloat16* h2     = (__hip_bfloat16*)alloc((size_t)n_nodes * 16 * 2);
    float*          hroot  = (float*)alloc((size_t)n_nodes * 16 * 4);
    float*          h      = xroot;

    // dense pre-transform
    dense1_kernel<<<(n_nodes + D1N - 1) / D1N, NT, 0, stream>>>(
        x, W1_rel, b1_rel, W1_root, xr, xroot, n_nodes);

    // bucket build -> packed -> CSR
    bucket_count<<<NCHUNK, BT, 0, stream>>>(dst, counts, n_edges, nbuckets, ept);
    bucket_totals<<<nbuckets, NPB, 0, stream>>>(counts, totals);
    scan_small<<<1, MAXB, 0, stream>>>(totals, bbase, nbuckets);
    scan_within<<<nbuckets, NPB, 0, stream>>>(counts, bbase);
    bucket_scatter<<<NCHUNK, BT, 0, stream>>>(src, dst, counts, packed,
                                              n_edges, nbuckets, ept);
    csr_build<<<nbuckets, NPB, 0, stream>>>(packed, counts, rowptr, csr,
                                            n_nodes, nbuckets, n_edges);

    // layer 1
    gather1_kernel<<<(n_nodes * H_SIZE + NT - 1) / NT, NT, 0, stream>>>(
        xr, xroot, rowptr, csr, h, n_nodes);

    // layer 2 + loss
    dense2_kernel<<<(n_nodes * 16 + NT - 1) / NT, NT, 0, stream>>>(
        h, W2_rel, b2_rel, W2_root, h2, hroot, n_nodes);
    hipMemsetAsync(loss, 0, sizeof(float), stream);
    gather2_loss_kernel<<<(n_nodes * 16 + NT - 1) / NT, NT, 0, stream>>>(
        h2, hroot, rowptr, csr, y, loss, n_nodes, 1.f / (float)n_nodes);
}

// Round 8
// 222.779 us; speedup vs baseline: 6.0707x; 1.1333x over previous
//
#include <hip/hip_runtime.h>
#include <hip/hip_bf16.h>

#define D_FEAT 64
#define H_SIZE 32
#define N_CLASSES 10
#define NPB 256          // nodes per bucket (bucket = dst >> 8)
#define MAXB 512
#define NCHUNK 256       // edge chunks for count/scatter passes
#define BT 1024
#define NT 256
#define D1N 64           // nodes per dense1 block

// ---------- dense1: xr(bf16) = x@W1_rel^T ; xroot = x@W1_root^T + b1 -------

__global__ __launch_bounds__(NT) void dense1_kernel(
    const float* __restrict__ x, const float* __restrict__ W1_rel,
    const float* __restrict__ b1, const float* __restrict__ W1_root,
    __hip_bfloat16* __restrict__ xr, float* __restrict__ xroot, int n_nodes) {
    __shared__ float sWrel[D_FEAT * 33];
    __shared__ float sWroot[D_FEAT * 33];
    __shared__ float sx[D1N * D_FEAT];
    __shared__ float sb[H_SIZE];
    int tid = threadIdx.x;
    for (int i = tid; i < H_SIZE * D_FEAT; i += NT) {
        int k = i >> 6, f = i & 63;          // W[k][f] row-major in
        sWrel[f * 33 + k] = W1_rel[i];       // bank (f+k)%32 -> conflict-free
        sWroot[f * 33 + k] = W1_root[i];
    }
    if (tid < H_SIZE) sb[tid] = b1[tid];

    int nbase = blockIdx.x * D1N;
    int nvalid = min(D1N, n_nodes - nbase);
    const float4* x4 = (const float4*)(x + (size_t)nbase * D_FEAT);
    float4* sx4 = (float4*)sx;
    for (int i = tid; i < nvalid * (D_FEAT / 4); i += NT) sx4[i] = x4[i];
    __syncthreads();

    int k = tid & 31, g = tid >> 5;          // 8 node-groups of 8
#pragma unroll
    for (int j = 0; j < 2; ++j) {
        int nl = g * 8 + j * 4;
        if (nl >= nvalid) break;
        int last = nvalid - 1;
        const float* r0 = sx + min(nl + 0, last) * D_FEAT;
        const float* r1 = sx + min(nl + 1, last) * D_FEAT;
        const float* r2 = sx + min(nl + 2, last) * D_FEAT;
        const float* r3 = sx + min(nl + 3, last) * D_FEAT;
        float a0 = 0.f, a1 = 0.f, a2 = 0.f, a3 = 0.f;
        float o0 = 0.f, o1 = 0.f, o2 = 0.f, o3 = 0.f;
#pragma unroll
        for (int f = 0; f < D_FEAT; ++f) {
            float wr = sWrel[f * 33 + k];
            float wo = sWroot[f * 33 + k];
            float v0 = r0[f], v1 = r1[f], v2 = r2[f], v3 = r3[f];
            a0 += v0 * wr; a1 += v1 * wr; a2 += v2 * wr; a3 += v3 * wr;
            o0 += v0 * wo; o1 += v1 * wo; o2 += v2 * wo; o3 += v3 * wo;
        }
        float bk = sb[k];
#pragma unroll
        for (int u = 0; u < 4; ++u) {
            int nn = nl + u;
            if (nn < nvalid) {
                size_t idx = (size_t)(nbase + nn) * H_SIZE + k;
                float ar = (u == 0) ? a0 : (u == 1) ? a1 : (u == 2) ? a2 : a3;
                float ao = (u == 0) ? o0 : (u == 1) ? o1 : (u == 2) ? o2 : o3;
                xr[idx] = __float2bfloat16(ar);
                xroot[idx] = ao + bk;
            }
        }
    }
}

// ---------- bucket count -> hierarchical scan -> scatter -------------------

__global__ __launch_bounds__(BT) void bucket_count(
    const int* __restrict__ dst, int* __restrict__ counts,
    int n_edges, int nbuckets, int ept) {
    __shared__ int hist[MAXB];
    for (int i = threadIdx.x; i < nbuckets; i += BT) hist[i] = 0;
    __syncthreads();
    int beg = blockIdx.x * ept;
    int end = min(beg + ept, n_edges);
    for (int e = beg + threadIdx.x; e < end; e += BT)
        atomicAdd(&hist[dst[e] >> 8], 1);
    __syncthreads();
    for (int b = threadIdx.x; b < nbuckets; b += BT)
        counts[b * NCHUNK + blockIdx.x] = hist[b];
}

__global__ __launch_bounds__(NPB) void bucket_totals(
    const int* __restrict__ counts, int* __restrict__ totals) {
    int b = blockIdx.x, tid = threadIdx.x;
    int v = counts[b * NCHUNK + tid];
#pragma unroll
    for (int o = 32; o > 0; o >>= 1) v += __shfl_down(v, o, 64);
    __shared__ int part[NPB / 64];
    if ((tid & 63) == 0) part[tid >> 6] = v;
    __syncthreads();
    if (tid == 0) {
        int s = 0;
#pragma unroll
        for (int w = 0; w < NPB / 64; ++w) s += part[w];
        totals[b] = s;
    }
}

__global__ __launch_bounds__(MAXB) void scan_small(
    const int* __restrict__ totals, int* __restrict__ bbase, int nbuckets) {
    __shared__ int lds[MAXB];
    int tid = threadIdx.x;
    int v = (tid < nbuckets) ? totals[tid] : 0;
    lds[tid] = v;
    __syncthreads();
    for (int off = 1; off < MAXB; off <<= 1) {
        int t = (tid >= off) ? lds[tid - off] : 0;
        __syncthreads();
        lds[tid] += t;
        __syncthreads();
    }
    if (tid < nbuckets) bbase[tid] = lds[tid] - v;
}

__global__ __launch_bounds__(NPB) void scan_within(
    int* __restrict__ counts, const int* __restrict__ bbase) {
    __shared__ int lds[NPB];
    int b = blockIdx.x, tid = threadIdx.x;
    int v = counts[b * NCHUNK + tid];
    lds[tid] = v;
    __syncthreads();
    for (int off = 1; off < NPB; off <<= 1) {
        int t = (tid >= off) ? lds[tid - off] : 0;
        __syncthreads();
        lds[tid] += t;
        __syncthreads();
    }
    counts[b * NCHUNK + tid] = bbase[b] + lds[tid] - v;
}

__global__ __launch_bounds__(BT) void bucket_scatter(
    const int* __restrict__ src, const int* __restrict__ dst,
    const int* __restrict__ base, unsigned* __restrict__ packed,
    int n_edges, int nbuckets, int ept) {
    __shared__ int cur[MAXB];
    for (int b = threadIdx.x; b < nbuckets; b += BT)
        cur[b] = base[b * NCHUNK + blockIdx.x];
    __syncthreads();
    int beg = blockIdx.x * ept;
    int end = min(beg + ept, n_edges);
    for (int e = beg + threadIdx.x; e < end; e += BT) {
        int s = src[e], d = dst[e];
        int slot = atomicAdd(&cur[d >> 8], 1);
        packed[slot] = (unsigned)s | ((unsigned)(d & 255) << 24);
    }
}

// ---------- per-bucket counting sort -> global CSR -------------------------

__global__ __launch_bounds__(NPB) void csr_build(
    const unsigned* __restrict__ packed, const int* __restrict__ base,
    int* __restrict__ rowptr, int* __restrict__ csr,
    int n_nodes, int nbuckets, int n_edges) {
    __shared__ int cnt[NPB];
    __shared__ int cur[NPB];
    int b = blockIdx.x, tid = threadIdx.x;
    int pBeg = base[b * NCHUNK];
    int pEnd = (b + 1 < nbuckets) ? base[(b + 1) * NCHUNK] : n_edges;
    cnt[tid] = 0;
    __syncthreads();
    for (int i = pBeg + tid; i < pEnd; i += NPB)
        atomicAdd(&cnt[packed[i] >> 24], 1);
    __syncthreads();
    int v = cnt[tid];
    cur[tid] = v;
    __syncthreads();
    for (int off = 1; off < NPB; off <<= 1) {
        int t = (tid >= off) ? cur[tid - off] : 0;
        __syncthreads();
        cur[tid] += t;
        __syncthreads();
    }
    int gbase = pBeg + cur[tid] - v;
    int n = (b << 8) + tid;
    if (n < n_nodes) rowptr[n] = gbase;
    if (b == nbuckets - 1 && tid == 0) rowptr[n_nodes] = n_edges;
    cur[tid] = gbase;
    __syncthreads();
    for (int i = pBeg + tid; i < pEnd; i += NPB) {
        unsigned p = packed[i];
        int slot = atomicAdd(&cur[p >> 24], 1);
        csr[slot] = (int)(p & 0xFFFFFF);
    }
}

// ---------- gather1 (+fused dense2): 16 lanes/node, packed dword loads -----
// h = relu(sum xr[neighbors] + xroot); then h2 = h@W2_rel^T (bf16),
// hroot = h@W2_root^T + b2, all without materializing h globally.

__global__ __launch_bounds__(NT) void gather1_kernel(
    const unsigned* __restrict__ xr2,      // bf16-pair view of xr [n*16+f2]
    const float* __restrict__ xroot,       // f32 [n*32]
    const int* __restrict__ rowptr, const int* __restrict__ csr,
    const float* __restrict__ W2_rel, const float* __restrict__ b2,
    const float* __restrict__ W2_root,
    __hip_bfloat16* __restrict__ h2, float* __restrict__ hroot, int n_nodes) {
    __shared__ float sWrelT[H_SIZE * 17];  // [j][c] stride 17
    __shared__ float sWrootT[H_SIZE * 17];
    __shared__ float sb[16];
    __shared__ float sh[16][34];           // 16 nodes/block, 32 feats pad 34
    int tid = threadIdx.x;
    for (int i = tid; i < H_SIZE * 17; i += NT) { sWrelT[i] = 0.f; sWrootT[i] = 0.f; }
    __syncthreads();
    for (int i = tid; i < N_CLASSES * H_SIZE; i += NT) {
        int c = i >> 5, j = i & 31;        // W2[c][j]
        sWrelT[j * 17 + c] = W2_rel[i];
        sWrootT[j * 17 + c] = W2_root[i];
    }
    if (tid < 16) sb[tid] = (tid < N_CLASSES) ? b2[tid] : 0.f;

    int t = blockIdx.x * NT + tid;
    int n = t >> 4, f2 = t & 15;
    int nl = tid >> 4;
    float a0 = 0.f, a1 = 0.f;
    if (n < n_nodes) {
        int beg = rowptr[n], end = rowptr[n + 1];
        int nfull = (end - beg) & ~15;
        int i = beg;
        for (; i < beg + nfull; i += 16) {         // full batches: no predication
            int e = csr[i + f2];
#pragma unroll
            for (int j = 0; j < 16; ++j) {
                int s = __shfl(e, j, 16);
                unsigned p = xr2[(size_t)s * 16 + f2];
                a0 += __uint_as_float(p << 16);
                a1 += __uint_as_float(p & 0xFFFF0000u);
            }
        }
        if (i < end) {                             // tail batch: predicated
            int cnt = end - i;
            int e = csr[i + ((f2 < cnt) ? f2 : cnt - 1)];
#pragma unroll
            for (int j = 0; j < 16; ++j) {
                int s = __shfl(e, j, 16);
                unsigned p = xr2[(size_t)s * 16 + f2];
                if (j < cnt) {
                    a0 += __uint_as_float(p << 16);
                    a1 += __uint_as_float(p & 0xFFFF0000u);
                }
            }
        }
        float2 x0 = ((const float2*)xroot)[(size_t)n * 16 + f2];
        a0 = fmaxf(a0 + x0.x, 0.f);
        a1 = fmaxf(a1 + x0.y, 0.f);
    }
    sh[nl][2 * f2] = a0;
    sh[nl][2 * f2 + 1] = a1;
    __syncthreads();

    // fused dense2 epilogue: thread (nl, c)
    int c = tid & 15;
    int n2 = blockIdx.x * 16 + nl;
    if (n2 < n_nodes) {
        float ar = 0.f, ao = 0.f;
#pragma unroll
        for (int j = 0; j < H_SIZE; ++j) {
            float hv = sh[nl][j];
            ar += hv * sWrelT[j * 17 + c];
            ao += hv * sWrootT[j * 17 + c];
        }
        h2[(size_t)n2 * 16 + c] = __float2bfloat16(ar);
        hroot[(size_t)n2 * 16 + c] = ao + sb[c];
    }
}

// ---------- gather2 + log-softmax + NLL: 8 lanes/node, packed dword loads --

__global__ __launch_bounds__(NT) void gather2_loss_kernel(
    const unsigned* __restrict__ h2u,      // bf16-pair view of h2 [n*8+c2]
    const float* __restrict__ hroot,
    const int* __restrict__ rowptr, const int* __restrict__ csr,
    const int* __restrict__ y, float* __restrict__ loss,
    int n_nodes, float invN) {
    int t = blockIdx.x * NT + threadIdx.x;
    int n = t >> 3, c2 = t & 7;
    int lane = threadIdx.x & 63;
    bool active = (n < n_nodes);

    float a0 = 0.f, a1 = 0.f;
    int yv = 0;
    if (active) {
        int beg = rowptr[n], end = rowptr[n + 1];
        int nfull = (end - beg) & ~7;
        int i = beg;
        for (; i < beg + nfull; i += 8) {          // full batches
            int e = csr[i + c2];
#pragma unroll
            for (int j = 0; j < 8; ++j) {
                int s = __shfl(e, j, 8);
                unsigned p = h2u[(size_t)s * 8 + c2];
                a0 += __uint_as_float(p << 16);
                a1 += __uint_as_float(p & 0xFFFF0000u);
            }
        }
        if (i < end) {                             // tail
            int cnt = end - i;
            int e = csr[i + ((c2 < cnt) ? c2 : cnt - 1)];
#pragma unroll
            for (int j = 0; j < 8; ++j) {
                int s = __shfl(e, j, 8);
                unsigned p = h2u[(size_t)s * 8 + c2];
                if (j < cnt) {
                    a0 += __uint_as_float(p << 16);
                    a1 += __uint_as_float(p & 0xFFFF0000u);
                }
            }
        }
        float2 hr = ((const float2*)hroot)[(size_t)n * 8 + c2];
        a0 += hr.x; a1 += hr.y;
        yv = y[n];
    }
    // softmax over classes 0..9 (lanes c2<5 hold 2 valid classes each)
    bool cv = active && (c2 < 5);
    float lm = cv ? fmaxf(a0, a1) : -INFINITY;
#pragma unroll
    for (int m = 1; m < 8; m <<= 1) lm = fmaxf(lm, __shfl_xor(lm, m, 64));
    float es = cv ? (expf(a0 - lm) + expf(a1 - lm)) : 0.f;
#pragma unroll
    for (int m = 1; m < 8; m <<= 1) es += __shfl_xor(es, m, 64);
    int srcl = (lane & ~7) + (yv >> 1);
    float ly0 = __shfl(a0, srcl, 64);
    float ly1 = __shfl(a1, srcl, 64);
    float ly = (yv & 1) ? ly1 : ly0;
    float contrib = (active && c2 == 0) ? (lm + logf(es) - ly) * invN : 0.f;

#pragma unroll
    for (int o = 32; o > 0; o >>= 1) contrib += __shfl_down(contrib, o, 64);
    __shared__ float part[NT / 64];
    if (lane == 0) part[threadIdx.x >> 6] = contrib;
    __syncthreads();
    if (threadIdx.x == 0) {
        float v = 0.f;
#pragma unroll
        for (int w = 0; w < NT / 64; ++w) v += part[w];
        atomicAdd(loss, v);
    }
}

// ---------------------------------------------------------------------------

extern "C" void kernel_launch(void* const* d_in, const int* in_sizes, int n_in,
                              void* d_out, int out_size, void* d_ws, size_t ws_size,
                              hipStream_t stream) {
    const float* x       = (const float*)d_in[0];
    const int*   ei      = (const int*)d_in[1];
    const int*   y       = (const int*)d_in[2];
    const float* W1_rel  = (const float*)d_in[3];
    const float* b1_rel  = (const float*)d_in[4];
    const float* W1_root = (const float*)d_in[5];
    const float* W2_rel  = (const float*)d_in[6];
    const float* b2_rel  = (const float*)d_in[7];
    const float* W2_root = (const float*)d_in[8];
    float* loss = (float*)d_out;

    const int n_nodes = in_sizes[0] / D_FEAT;
    const int n_edges = in_sizes[1] / 2;
    const int* src = ei;
    const int* dst = ei + n_edges;

    const int nbuckets = (n_nodes + NPB - 1) / NPB;
    const int M = nbuckets * NCHUNK;
    const int ept = (n_edges + NCHUNK - 1) / NCHUNK;

    size_t off = 0;
    auto alloc = [&](size_t bytes) {
        void* p = (char*)d_ws + off;
        off = (off + bytes + 255) & ~(size_t)255;
        return p;
    };
    int*            counts = (int*)alloc((size_t)(M + 1) * 4);
    int*            totals = (int*)alloc((size_t)MAXB * 4);
    int*            bbase  = (int*)alloc((size_t)MAXB * 4);
    unsigned*       packed = (unsigned*)alloc((size_t)n_edges * 4);
    int*            rowptr = (int*)alloc((size_t)(n_nodes + 1) * 4);
    int*            csr    = (int*)alloc((size_t)n_edges * 4);
    __hip_bfloat16* xr     = (__hip_bfloat16*)alloc((size_t)n_nodes * H_SIZE * 2);
    float*          xroot  = (float*)alloc((size_t)n_nodes * H_SIZE * 4);
    __hip_bfloat16* h2     = (__hip_bfloat16*)alloc((size_t)n_nodes * 16 * 2);
    float*          hroot  = (float*)alloc((size_t)n_nodes * 16 * 4);

    // dense pre-transform
    dense1_kernel<<<(n_nodes + D1N - 1) / D1N, NT, 0, stream>>>(
        x, W1_rel, b1_rel, W1_root, xr, xroot, n_nodes);

    // bucket build -> packed -> CSR
    bucket_count<<<NCHUNK, BT, 0, stream>>>(dst, counts, n_edges, nbuckets, ept);
    bucket_totals<<<nbuckets, NPB, 0, stream>>>(counts, totals);
    scan_small<<<1, MAXB, 0, stream>>>(totals, bbase, nbuckets);
    scan_within<<<nbuckets, NPB, 0, stream>>>(counts, bbase);
    bucket_scatter<<<NCHUNK, BT, 0, stream>>>(src, dst, counts, packed,
                                              n_edges, nbuckets, ept);
    csr_build<<<nbuckets, NPB, 0, stream>>>(packed, counts, rowptr, csr,
                                            n_nodes, nbuckets, n_edges);

    // layer 1 aggregate + fused dense2 (16 nodes per block)
    gather1_kernel<<<(n_nodes + 15) / 16, NT, 0, stream>>>(
        (const unsigned*)xr, xroot, rowptr, csr,
        W2_rel, b2_rel, W2_root, h2, hroot, n_nodes);

    // layer 2 aggregate + loss (32 nodes per block)
    hipMemsetAsync(loss, 0, sizeof(float), stream);
    gather2_loss_kernel<<<(n_nodes + 31) / 32, NT, 0, stream>>>(
        (const unsigned*)h2, hroot, rowptr, csr, y, loss,
        n_nodes, 1.f / (float)n_nodes);
}

// Round 9
// 163.869 us; speedup vs baseline: 8.2531x; 1.3595x over previous
//
#include <hip/hip_runtime.h>
#include <hip/hip_bf16.h>
#include <hip/hip_fp8.h>

#define D_FEAT 64
#define H_SIZE 32
#define N_CLASSES 10
#define NPB 256          // nodes per bucket (bucket = dst >> 8)
#define MAXB 512
#define NCHUNK 256       // edge chunks for count/scatter passes
#define BT 1024
#define NT 256

using short8 = __attribute__((ext_vector_type(8))) short;
using f32x4v = __attribute__((ext_vector_type(4))) float;

__device__ inline short f2bf(float f) {
    __hip_bfloat16 h = __float2bfloat16(f);
    return *reinterpret_cast<short*>(&h);
}

// ---------- dense1 via MFMA: O = x @ [W1_rel^T | W1_root^T] ---------------
// xr (fp8, cols 0..31) ; xroot = cols 32..63 + b1 (f32)

__global__ __launch_bounds__(NT) void dense1_mfma(
    const float* __restrict__ x, const float* __restrict__ W1_rel,
    const float* __restrict__ b1, const float* __restrict__ W1_root,
    unsigned* __restrict__ xr8, float* __restrict__ xroot, int n_nodes) {
    __shared__ unsigned short sW[64 * 72];   // [outcol n][k] bf16, pad 72
    __shared__ float sOut[64 * 65];          // [node][outcol] f32, pad 65
    __shared__ float sb[H_SIZE];
    int tid = threadIdx.x;
    for (int i = tid; i < 64 * 64; i += NT) {
        int n = i >> 6, k = i & 63;
        float w = (n < 32) ? W1_rel[n * 64 + k] : W1_root[(n - 32) * 64 + k];
        sW[n * 72 + k] = (unsigned short)f2bf(w);
    }
    if (tid < H_SIZE) sb[tid] = b1[tid];
    __syncthreads();

    int lane = tid & 63, wave = tid >> 6;
    int r16 = lane & 15, h = lane >> 4;      // h in 0..3

    // B fragments: b[t][s]  t = 16-wide n-tile (0..3), s = 32-wide k-step (0..1)
    short8 bf[4][2];
#pragma unroll
    for (int t = 0; t < 4; ++t)
#pragma unroll
        for (int s = 0; s < 2; ++s) {
            const unsigned short* p = &sW[(t * 16 + r16) * 72 + s * 32 + h * 8];
            bf[t][s] = *reinterpret_cast<const short8*>(p);
        }

    int nbase = blockIdx.x * 64 + wave * 16;
    int row = nbase + r16;
    int rowc = min(row, n_nodes - 1);        // clamp; stores are guarded

    short8 af[2];
#pragma unroll
    for (int s = 0; s < 2; ++s) {
        const float* px = x + (size_t)rowc * D_FEAT + s * 32 + h * 8;
        float4 lo = *reinterpret_cast<const float4*>(px);
        float4 hi = *reinterpret_cast<const float4*>(px + 4);
        short8 a;
        a[0] = f2bf(lo.x); a[1] = f2bf(lo.y); a[2] = f2bf(lo.z); a[3] = f2bf(lo.w);
        a[4] = f2bf(hi.x); a[5] = f2bf(hi.y); a[6] = f2bf(hi.z); a[7] = f2bf(hi.w);
        af[s] = a;
    }

    f32x4v acc[4] = {{0.f,0.f,0.f,0.f},{0.f,0.f,0.f,0.f},
                     {0.f,0.f,0.f,0.f},{0.f,0.f,0.f,0.f}};
#pragma unroll
    for (int t = 0; t < 4; ++t) {
        acc[t] = __builtin_amdgcn_mfma_f32_16x16x32_bf16(af[0], bf[t][0], acc[t], 0, 0, 0);
        acc[t] = __builtin_amdgcn_mfma_f32_16x16x32_bf16(af[1], bf[t][1], acc[t], 0, 0, 0);
    }
    // C/D layout (verified): col = lane&15, row = (lane>>4)*4 + reg
#pragma unroll
    for (int t = 0; t < 4; ++t)
#pragma unroll
        for (int r = 0; r < 4; ++r)
            sOut[(wave * 16 + h * 4 + r) * 65 + t * 16 + r16] = acc[t][r];
    __syncthreads();

    // writeout: wave0/1 -> xr fp8 halves; wave2/3 -> xroot halves (+bias)
    int nl = lane;
    int g = blockIdx.x * 64 + nl;
    if (g < n_nodes) {
        if (wave < 2) {
            unsigned w4[4];
#pragma unroll
            for (int q = 0; q < 4; ++q) {
                unsigned wd = 0;
#pragma unroll
                for (int b = 0; b < 4; ++b) {
                    float v = sOut[nl * 65 + wave * 16 + q * 4 + b];
                    __hip_fp8_e4m3 f8(v);
                    wd |= ((unsigned)f8.__x) << (8 * b);
                }
                w4[q] = wd;
            }
            *reinterpret_cast<uint4*>(&xr8[(size_t)g * 8 + wave * 4]) =
                make_uint4(w4[0], w4[1], w4[2], w4[3]);
        } else {
            int co = (wave - 2) * 16;
#pragma unroll
            for (int q = 0; q < 4; ++q) {
                float4 v;
                v.x = sOut[nl * 65 + 32 + co + q * 4 + 0] + sb[co + q * 4 + 0];
                v.y = sOut[nl * 65 + 32 + co + q * 4 + 1] + sb[co + q * 4 + 1];
                v.z = sOut[nl * 65 + 32 + co + q * 4 + 2] + sb[co + q * 4 + 2];
                v.w = sOut[nl * 65 + 32 + co + q * 4 + 3] + sb[co + q * 4 + 3];
                *reinterpret_cast<float4*>(&xroot[(size_t)g * 32 + co + q * 4]) = v;
            }
        }
    }
}

// ---------- bucket count -> hierarchical scan -> scatter -------------------

__global__ __launch_bounds__(BT) void bucket_count(
    const int* __restrict__ dst, int* __restrict__ counts,
    int n_edges, int nbuckets, int ept) {
    __shared__ int hist[MAXB];
    for (int i = threadIdx.x; i < nbuckets; i += BT) hist[i] = 0;
    __syncthreads();
    int beg = blockIdx.x * ept;
    int end = min(beg + ept, n_edges);
    for (int e = beg + threadIdx.x; e < end; e += BT)
        atomicAdd(&hist[dst[e] >> 8], 1);
    __syncthreads();
    for (int b = threadIdx.x; b < nbuckets; b += BT)
        counts[b * NCHUNK + blockIdx.x] = hist[b];
}

__global__ __launch_bounds__(NPB) void bucket_totals(
    const int* __restrict__ counts, int* __restrict__ totals) {
    int b = blockIdx.x, tid = threadIdx.x;
    int v = counts[b * NCHUNK + tid];
#pragma unroll
    for (int o = 32; o > 0; o >>= 1) v += __shfl_down(v, o, 64);
    __shared__ int part[NPB / 64];
    if ((tid & 63) == 0) part[tid >> 6] = v;
    __syncthreads();
    if (tid == 0) {
        int s = 0;
#pragma unroll
        for (int w = 0; w < NPB / 64; ++w) s += part[w];
        totals[b] = s;
    }
}

__global__ __launch_bounds__(MAXB) void scan_small(
    const int* __restrict__ totals, int* __restrict__ bbase, int nbuckets) {
    __shared__ int lds[MAXB];
    int tid = threadIdx.x;
    int v = (tid < nbuckets) ? totals[tid] : 0;
    lds[tid] = v;
    __syncthreads();
    for (int off = 1; off < MAXB; off <<= 1) {
        int t = (tid >= off) ? lds[tid - off] : 0;
        __syncthreads();
        lds[tid] += t;
        __syncthreads();
    }
    if (tid < nbuckets) bbase[tid] = lds[tid] - v;
}

__global__ __launch_bounds__(NPB) void scan_within(
    int* __restrict__ counts, const int* __restrict__ bbase) {
    __shared__ int lds[NPB];
    int b = blockIdx.x, tid = threadIdx.x;
    int v = counts[b * NCHUNK + tid];
    lds[tid] = v;
    __syncthreads();
    for (int off = 1; off < NPB; off <<= 1) {
        int t = (tid >= off) ? lds[tid - off] : 0;
        __syncthreads();
        lds[tid] += t;
        __syncthreads();
    }
    counts[b * NCHUNK + tid] = bbase[b] + lds[tid] - v;
}

__global__ __launch_bounds__(BT) void bucket_scatter(
    const int* __restrict__ src, const int* __restrict__ dst,
    const int* __restrict__ base, unsigned* __restrict__ packed,
    int n_edges, int nbuckets, int ept) {
    __shared__ int cur[MAXB];
    for (int b = threadIdx.x; b < nbuckets; b += BT)
        cur[b] = base[b * NCHUNK + blockIdx.x];
    __syncthreads();
    int beg = blockIdx.x * ept;
    int end = min(beg + ept, n_edges);
    for (int e = beg + threadIdx.x; e < end; e += BT) {
        int s = src[e], d = dst[e];
        int slot = atomicAdd(&cur[d >> 8], 1);
        packed[slot] = (unsigned)s | ((unsigned)(d & 255) << 24);
    }
}

// ---------- per-bucket counting sort -> global CSR -------------------------

__global__ __launch_bounds__(NPB) void csr_build(
    const unsigned* __restrict__ packed, const int* __restrict__ base,
    int* __restrict__ rowptr, int* __restrict__ csr,
    int n_nodes, int nbuckets, int n_edges) {
    __shared__ int cnt[NPB];
    __shared__ int cur[NPB];
    int b = blockIdx.x, tid = threadIdx.x;
    int pBeg = base[b * NCHUNK];
    int pEnd = (b + 1 < nbuckets) ? base[(b + 1) * NCHUNK] : n_edges;
    cnt[tid] = 0;
    __syncthreads();
    for (int i = pBeg + tid; i < pEnd; i += NPB)
        atomicAdd(&cnt[packed[i] >> 24], 1);
    __syncthreads();
    int v = cnt[tid];
    cur[tid] = v;
    __syncthreads();
    for (int off = 1; off < NPB; off <<= 1) {
        int t = (tid >= off) ? cur[tid - off] : 0;
        __syncthreads();
        cur[tid] += t;
        __syncthreads();
    }
    int gbase = pBeg + cur[tid] - v;
    int n = (b << 8) + tid;
    if (n < n_nodes) rowptr[n] = gbase;
    if (b == nbuckets - 1 && tid == 0) rowptr[n_nodes] = n_edges;
    cur[tid] = gbase;
    __syncthreads();
    for (int i = pBeg + tid; i < pEnd; i += NPB) {
        unsigned p = packed[i];
        int slot = atomicAdd(&cur[p >> 24], 1);
        csr[slot] = (int)(p & 0xFFFFFF);
    }
}

// ---------- gather1 (+fused dense2): 8 lanes/node, fp8 dword loads ---------

__global__ __launch_bounds__(NT) void gather1_kernel(
    const unsigned* __restrict__ xr8, const float* __restrict__ xroot,
    const int* __restrict__ rowptr, const int* __restrict__ csr,
    const float* __restrict__ W2_rel, const float* __restrict__ b2,
    const float* __restrict__ W2_root,
    __hip_bfloat16* __restrict__ h2, float* __restrict__ hroot, int n_nodes) {
    __shared__ float sWrelT[H_SIZE * 17];  // [j][c] stride 17
    __shared__ float sWrootT[H_SIZE * 17];
    __shared__ float sb[16];
    __shared__ float sh[32][33];           // 32 nodes/block
    int tid = threadIdx.x;
    for (int i = tid; i < H_SIZE * 17; i += NT) { sWrelT[i] = 0.f; sWrootT[i] = 0.f; }
    __syncthreads();
    for (int i = tid; i < N_CLASSES * H_SIZE; i += NT) {
        int c = i >> 5, j = i & 31;
        sWrelT[j * 17 + c] = W2_rel[i];
        sWrootT[j * 17 + c] = W2_root[i];
    }
    if (tid < 16) sb[tid] = (tid < N_CLASSES) ? b2[tid] : 0.f;

    int t = blockIdx.x * NT + tid;
    int n = t >> 3, c2 = t & 7;            // c2 = dword index (feats 4c2..4c2+3)
    float a0 = 0.f, a1 = 0.f, a2 = 0.f, a3 = 0.f;
    if (n < n_nodes) {
        int beg = rowptr[n], end = rowptr[n + 1];
        int nfull = (end - beg) & ~7;
        int i = beg;
        for (; i < beg + nfull; i += 8) {          // full batches: no predication
            int e = csr[i + c2];
#pragma unroll
            for (int j = 0; j < 8; ++j) {
                int s = __shfl(e, j, 8);
                unsigned p = xr8[(size_t)s * 8 + c2];
                __hip_fp8_e4m3 f0, f1, f2, f3;
                f0.__x = (unsigned char)(p & 0xff);
                f1.__x = (unsigned char)((p >> 8) & 0xff);
                f2.__x = (unsigned char)((p >> 16) & 0xff);
                f3.__x = (unsigned char)(p >> 24);
                a0 += (float)f0; a1 += (float)f1; a2 += (float)f2; a3 += (float)f3;
            }
        }
        if (i < end) {                             // tail: predicated
            int cnt = end - i;
            int e = csr[i + ((c2 < cnt) ? c2 : cnt - 1)];
#pragma unroll
            for (int j = 0; j < 8; ++j) {
                int s = __shfl(e, j, 8);
                unsigned p = xr8[(size_t)s * 8 + c2];
                if (j < cnt) {
                    __hip_fp8_e4m3 f0, f1, f2, f3;
                    f0.__x = (unsigned char)(p & 0xff);
                    f1.__x = (unsigned char)((p >> 8) & 0xff);
                    f2.__x = (unsigned char)((p >> 16) & 0xff);
                    f3.__x = (unsigned char)(p >> 24);
                    a0 += (float)f0; a1 += (float)f1; a2 += (float)f2; a3 += (float)f3;
                }
            }
        }
        float4 xr4 = *reinterpret_cast<const float4*>(&xroot[(size_t)n * 32 + c2 * 4]);
        a0 = fmaxf(a0 + xr4.x, 0.f);
        a1 = fmaxf(a1 + xr4.y, 0.f);
        a2 = fmaxf(a2 + xr4.z, 0.f);
        a3 = fmaxf(a3 + xr4.w, 0.f);
    }
    int nl = tid >> 3;
    sh[nl][c2 * 4 + 0] = a0;
    sh[nl][c2 * 4 + 1] = a1;
    sh[nl][c2 * 4 + 2] = a2;
    sh[nl][c2 * 4 + 3] = a3;
    __syncthreads();

    // fused dense2: 32 nodes x 16 cols = 512 items, 2 passes
#pragma unroll
    for (int pass = 0; pass < 2; ++pass) {
        int idx = pass * NT + tid;
        int nl2 = idx >> 4, c = idx & 15;
        int n2 = blockIdx.x * 32 + nl2;
        if (n2 < n_nodes) {
            float ar = 0.f, ao = 0.f;
#pragma unroll
            for (int j = 0; j < H_SIZE; ++j) {
                float hv = sh[nl2][j];
                ar += hv * sWrelT[j * 17 + c];
                ao += hv * sWrootT[j * 17 + c];
            }
            h2[(size_t)n2 * 16 + c] = __float2bfloat16(ar);
            hroot[(size_t)n2 * 16 + c] = ao + sb[c];
        }
    }
}

// ---------- gather2 + log-softmax + NLL: 8 lanes/node, packed dword loads --

__global__ __launch_bounds__(NT) void gather2_loss_kernel(
    const unsigned* __restrict__ h2u,      // bf16-pair view of h2 [n*8+c2]
    const float* __restrict__ hroot,
    const int* __restrict__ rowptr, const int* __restrict__ csr,
    const int* __restrict__ y, float* __restrict__ loss,
    int n_nodes, float invN) {
    int t = blockIdx.x * NT + threadIdx.x;
    int n = t >> 3, c2 = t & 7;
    int lane = threadIdx.x & 63;
    bool active = (n < n_nodes);

    float a0 = 0.f, a1 = 0.f;
    int yv = 0;
    if (active) {
        int beg = rowptr[n], end = rowptr[n + 1];
        int nfull = (end - beg) & ~7;
        int i = beg;
        for (; i < beg + nfull; i += 8) {
            int e = csr[i + c2];
#pragma unroll
            for (int j = 0; j < 8; ++j) {
                int s = __shfl(e, j, 8);
                unsigned p = h2u[(size_t)s * 8 + c2];
                a0 += __uint_as_float(p << 16);
                a1 += __uint_as_float(p & 0xFFFF0000u);
            }
        }
        if (i < end) {
            int cnt = end - i;
            int e = csr[i + ((c2 < cnt) ? c2 : cnt - 1)];
#pragma unroll
            for (int j = 0; j < 8; ++j) {
                int s = __shfl(e, j, 8);
                unsigned p = h2u[(size_t)s * 8 + c2];
                if (j < cnt) {
                    a0 += __uint_as_float(p << 16);
                    a1 += __uint_as_float(p & 0xFFFF0000u);
                }
            }
        }
        float2 hr = ((const float2*)hroot)[(size_t)n * 8 + c2];
        a0 += hr.x; a1 += hr.y;
        yv = y[n];
    }
    bool cv = active && (c2 < 5);
    float lm = cv ? fmaxf(a0, a1) : -INFINITY;
#pragma unroll
    for (int m = 1; m < 8; m <<= 1) lm = fmaxf(lm, __shfl_xor(lm, m, 64));
    float es = cv ? (expf(a0 - lm) + expf(a1 - lm)) : 0.f;
#pragma unroll
    for (int m = 1; m < 8; m <<= 1) es += __shfl_xor(es, m, 64);
    int srcl = (lane & ~7) + (yv >> 1);
    float ly0 = __shfl(a0, srcl, 64);
    float ly1 = __shfl(a1, srcl, 64);
    float ly = (yv & 1) ? ly1 : ly0;
    float contrib = (active && c2 == 0) ? (lm + logf(es) - ly) * invN : 0.f;

#pragma unroll
    for (int o = 32; o > 0; o >>= 1) contrib += __shfl_down(contrib, o, 64);
    __shared__ float part[NT / 64];
    if (lane == 0) part[threadIdx.x >> 6] = contrib;
    __syncthreads();
    if (threadIdx.x == 0) {
        float v = 0.f;
#pragma unroll
        for (int w = 0; w < NT / 64; ++w) v += part[w];
        atomicAdd(loss, v);
    }
}

// ---------------------------------------------------------------------------

extern "C" void kernel_launch(void* const* d_in, const int* in_sizes, int n_in,
                              void* d_out, int out_size, void* d_ws, size_t ws_size,
                              hipStream_t stream) {
    const float* x       = (const float*)d_in[0];
    const int*   ei      = (const int*)d_in[1];
    const int*   y       = (const int*)d_in[2];
    const float* W1_rel  = (const float*)d_in[3];
    const float* b1_rel  = (const float*)d_in[4];
    const float* W1_root = (const float*)d_in[5];
    const float* W2_rel  = (const float*)d_in[6];
    const float* b2_rel  = (const float*)d_in[7];
    const float* W2_root = (const float*)d_in[8];
    float* loss = (float*)d_out;

    const int n_nodes = in_sizes[0] / D_FEAT;
    const int n_edges = in_sizes[1] / 2;
    const int* src = ei;
    const int* dst = ei + n_edges;

    const int nbuckets = (n_nodes + NPB - 1) / NPB;
    const int M = nbuckets * NCHUNK;
    const int ept = (n_edges + NCHUNK - 1) / NCHUNK;

    size_t off = 0;
    auto alloc = [&](size_t bytes) {
        void* p = (char*)d_ws + off;
        off = (off + bytes + 255) & ~(size_t)255;
        return p;
    };
    int*            counts = (int*)alloc((size_t)(M + 1) * 4);
    int*            totals = (int*)alloc((size_t)MAXB * 4);
    int*            bbase  = (int*)alloc((size_t)MAXB * 4);
    unsigned*       packed = (unsigned*)alloc((size_t)n_edges * 4);
    int*            rowptr = (int*)alloc((size_t)(n_nodes + 1) * 4);
    int*            csr    = (int*)alloc((size_t)n_edges * 4);
    unsigned*       xr8    = (unsigned*)alloc((size_t)n_nodes * 32);      // fp8 [n][32]
    float*          xroot  = (float*)alloc((size_t)n_nodes * H_SIZE * 4);
    __hip_bfloat16* h2     = (__hip_bfloat16*)alloc((size_t)n_nodes * 16 * 2);
    float*          hroot  = (float*)alloc((size_t)n_nodes * 16 * 4);

    // dense pre-transform via MFMA (64 nodes/block)
    dense1_mfma<<<(n_nodes + 63) / 64, NT, 0, stream>>>(
        x, W1_rel, b1_rel, W1_root, xr8, xroot, n_nodes);

    // bucket build -> packed -> CSR
    bucket_count<<<NCHUNK, BT, 0, stream>>>(dst, counts, n_edges, nbuckets, ept);
    bucket_totals<<<nbuckets, NPB, 0, stream>>>(counts, totals);
    scan_small<<<1, MAXB, 0, stream>>>(totals, bbase, nbuckets);
    scan_within<<<nbuckets, NPB, 0, stream>>>(counts, bbase);
    bucket_scatter<<<NCHUNK, BT, 0, stream>>>(src, dst, counts, packed,
                                              n_edges, nbuckets, ept);
    csr_build<<<nbuckets, NPB, 0, stream>>>(packed, counts, rowptr, csr,
                                            n_nodes, nbuckets, n_edges);

    // layer 1 aggregate + fused dense2 (32 nodes per block)
    gather1_kernel<<<(n_nodes + 31) / 32, NT, 0, stream>>>(
        xr8, xroot, rowptr, csr, W2_rel, b2_rel, W2_root, h2, hroot, n_nodes);

    // layer 2 aggregate + loss (32 nodes per block)
    hipMemsetAsync(loss, 0, sizeof(float), stream);
    gather2_loss_kernel<<<(n_nodes + 31) / 32, NT, 0, stream>>>(
        (const unsigned*)h2, hroot, rowptr, csr, y, loss,
        n_nodes, 1.f / (float)n_nodes);
}